// Round 16
// baseline (864.372 us; speedup 1.0000x reference)
//
#include <hip/hip_runtime.h>
#include <hip/hip_bf16.h>

#define NV 32000
#define NE 512
#define NH 512
#define NB 16
#define NT 128
#define NS 128

typedef __bf16 bf16x8 __attribute__((ext_vector_type(8)));
typedef float f32x4 __attribute__((ext_vector_type(4)));
typedef const __attribute__((address_space(1))) unsigned int gu32;
typedef __attribute__((address_space(3))) unsigned int lu32;

__device__ __forceinline__ float bits2f(unsigned int u) {
  union { unsigned int i; float f; } v; v.i = u; return v.f;
}

// ---------------- workspace layout (bytes) ----------------
static constexpr size_t HTAG_OFF  = 0;                                    // [2][16][512] u64
static constexpr size_t HDONE_OFF = HTAG_OFF + (size_t)2*NB*NH*8;         // [2048] u32
static constexpr size_t WHHT_OFF  = HDONE_OFF + 8192;                     // [512][1536] f32
static constexpr size_t GI_OFF    = WHHT_OFF + (size_t)3*NH*NH*4;         // [T][B][1536] f32
static constexpr size_t HALL_OFF  = GI_OFF + (size_t)NT*NB*3*NH*4;        // [T+1][B][512] f32
static constexpr size_t LWB_OFF   = HALL_OFF + (size_t)(NT+1)*NB*NH*4;    // [512][1024] bf16
static constexpr size_t ATTB_OFF  = LWB_OFF + (size_t)NH*2*NH*2;          // [B*T][512] bf16
static constexpr size_t OWB_OFF   = ATTB_OFF + (size_t)NB*NT*NH*2;        // [V][512] bf16
static constexpr size_t WS_NEED   = OWB_OFF + (size_t)NV*NH*2;            // ~55 MB

// ---------------- K1: merged prep + gi ----------------
__global__ __launch_bounds__(256) void k_pg(const int* __restrict__ tv,
                                            const float* __restrict__ emb,
                                            const float* __restrict__ w_ih,
                                            const float* __restrict__ b_ih,
                                            float* __restrict__ gi_all,
                                            const float* __restrict__ w_hh,
                                            const float* __restrict__ dh,
                                            const float* __restrict__ lin_w,
                                            float* __restrict__ whhT,
                                            float* __restrict__ h_all,
                                            unsigned short* __restrict__ lwb,
                                            unsigned long long* __restrict__ htag,
                                            unsigned int* __restrict__ hdone) {
  const int g = blockIdx.x;
  const int tid = threadIdx.x;
  if (g >= 768) {
    long long i0 = (long long)(g - 768) * 256 + tid;
    long long stride = (long long)256 * 256;
    for (long long i = i0; i < (long long)3 * NH * NH; i += stride) {
      int k = (int)(i / (3 * NH)), j = (int)(i % (3 * NH));
      whhT[i] = w_hh[(long long)j * NH + k];
    }
    // lin_w -> bf16
    for (long long i = i0; i < (long long)NH * 2 * NH / 4; i += stride) {
      float4 v = ((const float4*)lin_w)[i];
      union { __bf16 b[4]; unsigned long long u; } u4;
      u4.b[0] = (__bf16)v.x; u4.b[1] = (__bf16)v.y; u4.b[2] = (__bf16)v.z; u4.b[3] = (__bf16)v.w;
      *((unsigned long long*)(lwb + 4 * i)) = u4.u;
    }
    for (long long i = i0; i < NB * NH; i += stride) {
      float hv = dh[i];
      h_all[i] = hv;
      union { float f; unsigned u; } c; c.f = hv;
      htag[i] = (1ull << 32) | c.u;
      htag[NB * NH + i] = 0ull;
    }
    for (long long i = i0; i < 2048; i += stride) hdone[i] = 0u;
    return;
  }
  __shared__ float As[16][64];
  __shared__ float Bs[16][64];
  const int n0 = (g % 24) * 64;
  const int m0 = (g / 24) * 64;
  float acc[4][4] = {};
  const int rl = tid >> 2;
  const int kq = (tid & 3) * 4;
  const int tvr = tv[m0 + rl];
  const float* arow = emb + (long long)tvr * NE;
  const int tm = tid & 15, tn = tid >> 4;
  for (int k0 = 0; k0 < NE; k0 += 16) {
    __syncthreads();
    float4 av = make_float4(0.f, 0.f, 0.f, 0.f);
    if (tvr != 0) av = *(const float4*)(arow + k0 + kq);
    float4 bv = *(const float4*)(w_ih + (long long)(n0 + rl) * NE + k0 + kq);
    As[kq + 0][rl] = av.x; As[kq + 1][rl] = av.y; As[kq + 2][rl] = av.z; As[kq + 3][rl] = av.w;
    Bs[kq + 0][rl] = bv.x; Bs[kq + 1][rl] = bv.y; Bs[kq + 2][rl] = bv.z; Bs[kq + 3][rl] = bv.w;
    __syncthreads();
#pragma unroll
    for (int kk = 0; kk < 16; ++kk) {
      float4 a = *(const float4*)&As[kk][tm * 4];
      float4 b = *(const float4*)&Bs[kk][tn * 4];
      float ar[4] = {a.x, a.y, a.z, a.w}, br[4] = {b.x, b.y, b.z, b.w};
#pragma unroll
      for (int i = 0; i < 4; ++i)
#pragma unroll
        for (int j = 0; j < 4; ++j) acc[i][j] = fmaf(ar[i], br[j], acc[i][j]);
    }
  }
#pragma unroll
  for (int i = 0; i < 4; ++i) {
    int r = m0 + tm * 4 + i;
    long long gb = (long long)((r & 127) * 16 + (r >> 7)) * (3 * NH);
#pragma unroll
    for (int j = 0; j < 4; ++j) {
      int jg = n0 + tn * 4 + j;
      gi_all[gb + jg] = acc[i][j] + b_ih[jg];
    }
  }
}

// ---------------- K2: k_mid — rec (0..127) || conv+attn+att_lin (128..255) ----------------
// 256 blocks x 512 threads; 84KB LDS -> 1 block/CU (CU-exclusive), no VGPR spill.
__global__ __launch_bounds__(512, 1) void k_mid(const float* __restrict__ whhT,
                                                const float* __restrict__ gi_all,
                                                const float* __restrict__ b_hh,
                                                float* __restrict__ h_all,
                                                unsigned long long* __restrict__ htag,
                                                unsigned int* __restrict__ hdone,
                                                float* __restrict__ d_hf,
                                                const float* __restrict__ enc,
                                                const int* __restrict__ mask,
                                                const float* __restrict__ out_w,
                                                __bf16* __restrict__ owb,
                                                const unsigned short* __restrict__ lwb,
                                                float* __restrict__ d_attn,
                                                __bf16* __restrict__ attb) {
  __shared__ char smem_raw[86016];   // 84 KB fences to 1 block/CU
  float* smem = (float*)smem_raw;
  const int tid = threadIdx.x;
  const int bid = blockIdx.x;

  if (bid < 128) {
    // ================= recurrence — byte-identical protocol to R11 k_rec =================
    const int b = bid & 15, sub = bid >> 4;
    const int hl = tid & 63, kc = tid >> 6;   // 64 h x 8 k-chunks
    const int j = sub * 64 + hl;
    float* hbuf = smem;                       // [512]
    float* part = smem + 512;                 // [3][8][64]

    float wg[3][64];
#pragma unroll
    for (int g = 0; g < 3; ++g) {
      const float* wp = whhT + (long long)(kc * 64) * 1536 + g * 512 + j;
#pragma unroll
      for (int q = 0; q < 64; ++q) wg[g][q] = wp[(long long)q * 1536];
    }
    float bhr = 0.f, bhz = 0.f, bhn = 0.f;
    if (tid < 64) {
      bhr = b_hh[sub * 64 + tid];
      bhz = b_hh[512 + sub * 64 + tid];
      bhn = b_hh[1024 + sub * 64 + tid];
    }

    for (int t = 0; t < NT; ++t) {
      float gr = 0.f, gz = 0.f, gn = 0.f;
      if (tid < 64) {
        const float* gi = gi_all + (long long)(t * 16 + b) * 1536;
        gr = gi[sub * 64 + tid];
        gz = gi[512 + sub * 64 + tid];
        gn = gi[1024 + sub * 64 + tid];
      }
      {
        unsigned long long* slot = htag + ((long long)(t & 1) * NB + b) * 512 + tid;
        unsigned long long v = __hip_atomic_load(slot, __ATOMIC_RELAXED, __HIP_MEMORY_SCOPE_AGENT);
        int guard = 0;
        while ((unsigned)(v >> 32) != (unsigned)(t + 1) && ++guard < (1 << 22)) {
          v = __hip_atomic_load(slot, __ATOMIC_RELAXED, __HIP_MEMORY_SCOPE_AGENT);
        }
        union { unsigned u; float f; } c; c.u = (unsigned)v;
        hbuf[tid] = c.f;
      }
      __syncthreads();
      float ar = 0.f, az = 0.f, an = 0.f;
#pragma unroll
      for (int q4 = 0; q4 < 4; ++q4) {
        float4 h4[4];
#pragma unroll
        for (int u = 0; u < 4; ++u) h4[u] = *(const float4*)&hbuf[kc * 64 + q4 * 16 + u * 4];
#pragma unroll
        for (int u = 0; u < 4; ++u) {
          const float hh[4] = {h4[u].x, h4[u].y, h4[u].z, h4[u].w};
#pragma unroll
          for (int v = 0; v < 4; ++v) {
            const int q = q4 * 16 + u * 4 + v;
            ar = fmaf(hh[v], wg[0][q], ar);
            az = fmaf(hh[v], wg[1][q], az);
            an = fmaf(hh[v], wg[2][q], an);
          }
        }
      }
      part[(0 * 8 + kc) * 64 + hl] = ar;
      part[(1 * 8 + kc) * 64 + hl] = az;
      part[(2 * 8 + kc) * 64 + hl] = an;
      __syncthreads();
      if (tid < 64) {
        float sr = bhr, sz = bhz, sn = bhn;
#pragma unroll
        for (int c = 0; c < 8; ++c) {
          sr += part[(0 * 8 + c) * 64 + tid];
          sz += part[(1 * 8 + c) * 64 + tid];
          sn += part[(2 * 8 + c) * 64 + tid];
        }
        float r = 1.f / (1.f + expf(-(gr + sr)));
        float z = 1.f / (1.f + expf(-(gz + sz)));
        float n = tanhf(gn + r * sn);
        float hp = hbuf[sub * 64 + tid];
        float hv = (1.f - z) * n + z * hp;
        if (t < NT - 1) {
          union { float f; unsigned u; } c2; c2.f = hv;
          unsigned long long out = ((unsigned long long)(unsigned)(t + 2) << 32) | c2.u;
          __hip_atomic_store(htag + ((long long)((t + 1) & 1) * NB + b) * 512 + sub * 64 + tid, out,
                             __ATOMIC_RELAXED, __HIP_MEMORY_SCOPE_AGENT);
        }
        __hip_atomic_store(&h_all[(long long)((t + 1) * 16 + b) * 512 + sub * 64 + tid], hv,
                           __ATOMIC_RELAXED, __HIP_MEMORY_SCOPE_AGENT);
        if (t == NT - 1) d_hf[b * 512 + sub * 64 + tid] = hv;
      }
      __syncthreads();   // drains h stores before signaling
      if (tid == 0)
        __hip_atomic_fetch_add(&hdone[t * 16 + b], 1u, __ATOMIC_RELAXED, __HIP_MEMORY_SCOPE_AGENT);
    }
    return;
  }

  // ================= conv + attention + att_lin consumers (512 threads) =================
  const int cid = bid - 128;   // 0..127
  {
    long long n4 = (long long)NV * NH / 4;
    for (long long i = (long long)cid * 512 + tid; i < n4; i += (long long)128 * 512) {
      float4 v = ((const float4*)out_w)[i];
      union { __bf16 b[4]; float2 f2; } u;
      u.b[0] = (__bf16)v.x; u.b[1] = (__bf16)v.y; u.b[2] = (__bf16)v.z; u.b[3] = (__bf16)v.w;
      *((float2*)((__bf16*)owb + 4 * i)) = u.f2;
    }
  }
  float* hb = smem;            // [512]
  float* mixs = smem + 512;    // [512]
  float* red = smem + 1024;    // [512]
  float* wb = smem + 1536;     // [128]
  float* sred = smem + 1664;   // [2]
  for (int it = 0; it < 16; ++it) {
    const int u = it * 128 + cid;          // t-major -> earliest-ready order
    const int t = u >> 4, b = u & 15;
    if (tid == 0) {
      int guard = 0;
      while (__hip_atomic_load(&hdone[u], __ATOMIC_RELAXED, __HIP_MEMORY_SCOPE_AGENT) < 8u &&
             ++guard < (1 << 25)) {
        __builtin_amdgcn_s_sleep(4);
      }
    }
    __syncthreads();
    hb[tid] = __hip_atomic_load(&h_all[(long long)((t + 1) * 16 + b) * 512 + tid],
                                __ATOMIC_RELAXED, __HIP_MEMORY_SCOPE_AGENT);
    __syncthreads();
    // scores
    {
      const int s = tid & 127, q = tid >> 7;
      const float* erow = enc + (long long)(b * 128 + s) * 512 + q * 128;
      float p = 0.f;
#pragma unroll 8
      for (int k = 0; k < 128; ++k) p = fmaf(hb[q * 128 + k], erow[k], p);
      red[tid] = p;
    }
    __syncthreads();
    float sc = 0.f;
    if (tid < 128) {
      sc = red[tid] + red[tid + 128] + red[tid + 256] + red[tid + 384];
      if (mask[b * 128 + tid] == 0) sc = -1e6f;
      wb[tid] = sc;
    }
    __syncthreads();
    if (tid < 64) {
      float m2 = fmaxf(wb[tid], wb[tid + 64]);
      for (int off = 32; off; off >>= 1) m2 = fmaxf(m2, __shfl_down(m2, off));
      if (tid == 0) sred[0] = m2;
    }
    __syncthreads();
    if (tid < 128) wb[tid] = expf(sc - sred[0]);
    __syncthreads();
    if (tid < 64) {
      float s2 = wb[tid] + wb[tid + 64];
      for (int off = 32; off; off >>= 1) s2 += __shfl_down(s2, off);
      if (tid == 0) sred[1] = s2;
    }
    __syncthreads();
    {
      float inv = 1.f / sred[1];
      if (tid < 128) {
        float w = wb[tid] * inv;
        wb[tid] = w;
        d_attn[(long long)u * 128 + tid] = w;
      }
    }
    __syncthreads();
    // mix into LDS
    {
      float m = 0.f;
#pragma unroll 8
      for (int s2 = 0; s2 < 128; ++s2)
        m = fmaf(wb[s2], enc[(long long)(b * 128 + s2) * 512 + tid], m);
      mixs[tid] = m;
    }
    __syncthreads();
    // att_lin: o = tid; attended = tanh(sum_k comb[k] * lwb[o][k])  (bf16 weights)
    {
      float acc = 0.f;
      const unsigned short* wrow = lwb + (long long)tid * 1024;
#pragma unroll 4
      for (int k8 = 0; k8 < 128; ++k8) {
        uint4 w8 = *(const uint4*)(wrow + k8 * 8);
        const float* csrc = (k8 < 64) ? &hb[k8 * 8] : &mixs[(k8 - 64) * 8];
        float4 ca = *(const float4*)csrc;
        float4 cb = *(const float4*)(csrc + 4);
        acc = fmaf(ca.x, bits2f(w8.x << 16), acc);
        acc = fmaf(ca.y, bits2f(w8.x & 0xffff0000u), acc);
        acc = fmaf(ca.z, bits2f(w8.y << 16), acc);
        acc = fmaf(ca.w, bits2f(w8.y & 0xffff0000u), acc);
        acc = fmaf(cb.x, bits2f(w8.z << 16), acc);
        acc = fmaf(cb.y, bits2f(w8.z & 0xffff0000u), acc);
        acc = fmaf(cb.z, bits2f(w8.w << 16), acc);
        acc = fmaf(cb.w, bits2f(w8.w & 0xffff0000u), acc);
      }
      attb[(long long)(b * 128 + t) * 512 + tid] = (__bf16)tanhf(acc);
    }
    __syncthreads();   // hb/mixs/red/wb reused next unit
  }
}

// ---------------- K3: scores = attended @ out_w^T + out_b  (bf16 MFMA, f32 out) ----------------
__global__ __launch_bounds__(256) void k_out(const __bf16* __restrict__ Abf,
                                             const __bf16* __restrict__ Bbf,
                                             const float* __restrict__ bias,
                                             float* __restrict__ Cout) {
  __shared__ __bf16 Al[128 * 32];
  __shared__ __bf16 Bl[128 * 32];
  const int tid = threadIdx.x;
  const int lane = tid & 63;
  const int wave = tid >> 6;
  const int wm = wave >> 1, wn = wave & 1;
  const int swz = (blockIdx.x & 7) * 500 + (blockIdx.x >> 3);
  const int m0 = (swz & 15) * 128, n0 = (swz >> 4) * 128;
  f32x4 acc[4][4] = {};
  const int lrow = lane >> 2;
  const int lcol = (lane & 3) * 8;
  const int lm = lane & 15, lc = lane >> 4;
  for (int ks = 0; ks < 16; ++ks) {
    const int k0 = ks * 32;
    __syncthreads();
#pragma unroll
    for (int i = 0; i < 2; ++i) {
      int chunk = wave * 2 + i;
      int r = chunk * 16 + lrow;
      const __bf16* ga = Abf + (long long)(m0 + r) * NH + k0 + lcol;
      const __bf16* gb = Bbf + (long long)(n0 + r) * NH + k0 + lcol;
      __builtin_amdgcn_global_load_lds((gu32*)ga, (lu32*)((char*)Al + chunk * 1024), 16, 0, 0);
      __builtin_amdgcn_global_load_lds((gu32*)gb, (lu32*)((char*)Bl + chunk * 1024), 16, 0, 0);
    }
    __syncthreads();
    bf16x8 af[4], bfr[4];
#pragma unroll
    for (int i = 0; i < 4; ++i) af[i] = *(const bf16x8*)&Al[(wm * 64 + i * 16 + lm) * 32 + lc * 8];
#pragma unroll
    for (int j = 0; j < 4; ++j) bfr[j] = *(const bf16x8*)&Bl[(wn * 64 + j * 16 + lm) * 32 + lc * 8];
#pragma unroll
    for (int i = 0; i < 4; ++i)
#pragma unroll
      for (int j = 0; j < 4; ++j)
        acc[i][j] = __builtin_amdgcn_mfma_f32_16x16x32_bf16(bfr[j], af[i], acc[i][j], 0, 0, 0);
  }
  float4 bv[4];
#pragma unroll
  for (int j = 0; j < 4; ++j)
    bv[j] = *(const float4*)&bias[n0 + wn * 64 + j * 16 + lc * 4];
#pragma unroll
  for (int i = 0; i < 4; ++i) {
    long long rbase = (long long)(m0 + wm * 64 + i * 16 + lm) * NV;
#pragma unroll
    for (int j = 0; j < 4; ++j) {
      int c = n0 + wn * 64 + j * 16 + lc * 4;
      float4 o;
      o.x = acc[i][j][0] + bv[j].x;
      o.y = acc[i][j][1] + bv[j].y;
      o.z = acc[i][j][2] + bv[j].z;
      o.w = acc[i][j][3] + bv[j].w;
      *(float4*)&Cout[rbase + c] = o;
    }
  }
}

// ---------------- launch ----------------
extern "C" void kernel_launch(void* const* d_in, const int* in_sizes, int n_in,
                              void* d_out, int out_size, void* d_ws, size_t ws_size,
                              hipStream_t stream) {
  const int* tv = (const int*)d_in[0];
  const float* dh = (const float*)d_in[1];
  const float* enc = (const float*)d_in[2];
  const int* mask = (const int*)d_in[3];
  const float* emb = (const float*)d_in[4];
  const float* w_ih = (const float*)d_in[5];
  const float* w_hh = (const float*)d_in[6];
  const float* b_ih = (const float*)d_in[7];
  const float* b_hh = (const float*)d_in[8];
  const float* lin_w = (const float*)d_in[9];
  const float* out_w = (const float*)d_in[10];
  const float* out_b = (const float*)d_in[11];
  float* dout = (float*)d_out;
  char* ws = (char*)d_ws;
  if (ws_size < WS_NEED) return;

  unsigned long long* htag = (unsigned long long*)(ws + HTAG_OFF);
  unsigned int* hdone = (unsigned int*)(ws + HDONE_OFF);
  float* whhT = (float*)(ws + WHHT_OFF);
  float* gi_all = (float*)(ws + GI_OFF);
  float* h_all = (float*)(ws + HALL_OFF);
  unsigned short* lwb = (unsigned short*)(ws + LWB_OFF);
  __bf16* attb = (__bf16*)(ws + ATTB_OFF);
  __bf16* owb = (__bf16*)(ws + OWB_OFF);

  float* d_scores = dout;                                  // [B,T,V]
  float* d_hf = dout + (long long)NB * NT * NV;            // [1,B,H]
  float* d_attn = d_hf + NB * NH;                          // [T,B,S]

  k_pg<<<1024, 256, 0, stream>>>(tv, emb, w_ih, b_ih, gi_all,
                                 w_hh, dh, lin_w, whhT, h_all, lwb, htag, hdone);
  k_mid<<<256, 512, 0, stream>>>(whhT, gi_all, b_hh, h_all, htag, hdone, d_hf,
                                 enc, mask, out_w, owb, lwb, d_attn, attb);
  k_out<<<4000, 256, 0, stream>>>(attb, owb, out_b, d_scores);
}

// Round 17
// 827.034 us; speedup vs baseline: 1.0451x; 1.0451x over previous
//
#include <hip/hip_runtime.h>
#include <hip/hip_bf16.h>

#define NV 32000
#define NE 512
#define NH 512
#define NB 16
#define NT 128
#define NS 128

typedef __bf16 bf16x8 __attribute__((ext_vector_type(8)));
typedef float f32x4 __attribute__((ext_vector_type(4)));
typedef const __attribute__((address_space(1))) unsigned int gu32;
typedef __attribute__((address_space(3))) unsigned int lu32;

__device__ __forceinline__ float bits2f(unsigned int u) {
  union { unsigned int i; float f; } v; v.i = u; return v.f;
}

// ---------------- workspace layout (bytes) ----------------
static constexpr size_t HTAG_OFF  = 0;                                    // [2][16][512] u64
static constexpr size_t HDONE_OFF = HTAG_OFF + (size_t)2*NB*NH*8;         // [2048] u32
static constexpr size_t WHHT_OFF  = HDONE_OFF + 8192;                     // [512][1536] f32
static constexpr size_t GI_OFF    = WHHT_OFF + (size_t)3*NH*NH*4;         // [T][B][1536] f32
static constexpr size_t HALL_OFF  = GI_OFF + (size_t)NT*NB*3*NH*4;        // [T+1][B][512] f32
static constexpr size_t LWB_OFF   = HALL_OFF + (size_t)(NT+1)*NB*NH*4;    // [512][1024] bf16
static constexpr size_t ATTB_OFF  = LWB_OFF + (size_t)NH*2*NH*2;          // [B*T][512] bf16
static constexpr size_t OWB_OFF   = ATTB_OFF + (size_t)NB*NT*NH*2;        // [V][512] bf16
static constexpr size_t WS_NEED   = OWB_OFF + (size_t)NV*NH*2;            // ~55 MB

// ---------------- K1: merged prep + gi ----------------
__global__ __launch_bounds__(256) void k_pg(const int* __restrict__ tv,
                                            const float* __restrict__ emb,
                                            const float* __restrict__ w_ih,
                                            const float* __restrict__ b_ih,
                                            float* __restrict__ gi_all,
                                            const float* __restrict__ w_hh,
                                            const float* __restrict__ dh,
                                            const float* __restrict__ lin_w,
                                            float* __restrict__ whhT,
                                            float* __restrict__ h_all,
                                            unsigned short* __restrict__ lwb,
                                            unsigned long long* __restrict__ htag,
                                            unsigned int* __restrict__ hdone) {
  const int g = blockIdx.x;
  const int tid = threadIdx.x;
  if (g >= 768) {
    long long i0 = (long long)(g - 768) * 256 + tid;
    long long stride = (long long)256 * 256;
    for (long long i = i0; i < (long long)3 * NH * NH; i += stride) {
      int k = (int)(i / (3 * NH)), j = (int)(i % (3 * NH));
      whhT[i] = w_hh[(long long)j * NH + k];
    }
    for (long long i = i0; i < (long long)NH * 2 * NH / 4; i += stride) {
      float4 v = ((const float4*)lin_w)[i];
      union { __bf16 b[4]; unsigned long long u; } u4;
      u4.b[0] = (__bf16)v.x; u4.b[1] = (__bf16)v.y; u4.b[2] = (__bf16)v.z; u4.b[3] = (__bf16)v.w;
      *((unsigned long long*)(lwb + 4 * i)) = u4.u;
    }
    for (long long i = i0; i < NB * NH; i += stride) {
      float hv = dh[i];
      h_all[i] = hv;
      union { float f; unsigned u; } c; c.f = hv;
      htag[i] = (1ull << 32) | c.u;
      htag[NB * NH + i] = 0ull;
    }
    for (long long i = i0; i < 2048; i += stride) hdone[i] = 0u;
    return;
  }
  __shared__ float As[16][64];
  __shared__ float Bs[16][64];
  const int n0 = (g % 24) * 64;
  const int m0 = (g / 24) * 64;
  float acc[4][4] = {};
  const int rl = tid >> 2;
  const int kq = (tid & 3) * 4;
  const int tvr = tv[m0 + rl];
  const float* arow = emb + (long long)tvr * NE;
  const int tm = tid & 15, tn = tid >> 4;
  for (int k0 = 0; k0 < NE; k0 += 16) {
    __syncthreads();
    float4 av = make_float4(0.f, 0.f, 0.f, 0.f);
    if (tvr != 0) av = *(const float4*)(arow + k0 + kq);
    float4 bv = *(const float4*)(w_ih + (long long)(n0 + rl) * NE + k0 + kq);
    As[kq + 0][rl] = av.x; As[kq + 1][rl] = av.y; As[kq + 2][rl] = av.z; As[kq + 3][rl] = av.w;
    Bs[kq + 0][rl] = bv.x; Bs[kq + 1][rl] = bv.y; Bs[kq + 2][rl] = bv.z; Bs[kq + 3][rl] = bv.w;
    __syncthreads();
#pragma unroll
    for (int kk = 0; kk < 16; ++kk) {
      float4 a = *(const float4*)&As[kk][tm * 4];
      float4 b = *(const float4*)&Bs[kk][tn * 4];
      float ar[4] = {a.x, a.y, a.z, a.w}, br[4] = {b.x, b.y, b.z, b.w};
#pragma unroll
      for (int i = 0; i < 4; ++i)
#pragma unroll
        for (int j = 0; j < 4; ++j) acc[i][j] = fmaf(ar[i], br[j], acc[i][j]);
    }
  }
#pragma unroll
  for (int i = 0; i < 4; ++i) {
    int r = m0 + tm * 4 + i;
    long long gb = (long long)((r & 127) * 16 + (r >> 7)) * (3 * NH);
#pragma unroll
    for (int j = 0; j < 4; ++j) {
      int jg = n0 + tn * 4 + j;
      gi_all[gb + jg] = acc[i][j] + b_ih[jg];
    }
  }
}

// ---------------- K2: k_mid — rec (0..127) || conv+attn+att_lin (128..255) ----------------
__global__ __launch_bounds__(512, 1) void k_mid(const float* __restrict__ whhT,
                                                const float* __restrict__ gi_all,
                                                const float* __restrict__ b_hh,
                                                float* __restrict__ h_all,
                                                unsigned long long* __restrict__ htag,
                                                unsigned int* __restrict__ hdone,
                                                float* __restrict__ d_hf,
                                                const float* __restrict__ enc,
                                                const int* __restrict__ mask,
                                                const float* __restrict__ out_w,
                                                __bf16* __restrict__ owb,
                                                const unsigned short* __restrict__ lwb,
                                                float* __restrict__ d_attn,
                                                __bf16* __restrict__ attb) {
  __shared__ char smem_raw[86016];   // 84 KB fences to 1 block/CU
  float* smem = (float*)smem_raw;
  const int tid = threadIdx.x;
  const int bid = blockIdx.x;

  if (bid < 128) {
    // ================= recurrence — byte-identical protocol to R11 k_rec =================
    const int b = bid & 15, sub = bid >> 4;
    const int hl = tid & 63, kc = tid >> 6;
    const int j = sub * 64 + hl;
    float* hbuf = smem;
    float* part = smem + 512;

    float wg[3][64];
#pragma unroll
    for (int g = 0; g < 3; ++g) {
      const float* wp = whhT + (long long)(kc * 64) * 1536 + g * 512 + j;
#pragma unroll
      for (int q = 0; q < 64; ++q) wg[g][q] = wp[(long long)q * 1536];
    }
    float bhr = 0.f, bhz = 0.f, bhn = 0.f;
    if (tid < 64) {
      bhr = b_hh[sub * 64 + tid];
      bhz = b_hh[512 + sub * 64 + tid];
      bhn = b_hh[1024 + sub * 64 + tid];
    }

    for (int t = 0; t < NT; ++t) {
      float gr = 0.f, gz = 0.f, gn = 0.f;
      if (tid < 64) {
        const float* gi = gi_all + (long long)(t * 16 + b) * 1536;
        gr = gi[sub * 64 + tid];
        gz = gi[512 + sub * 64 + tid];
        gn = gi[1024 + sub * 64 + tid];
      }
      {
        unsigned long long* slot = htag + ((long long)(t & 1) * NB + b) * 512 + tid;
        unsigned long long v = __hip_atomic_load(slot, __ATOMIC_RELAXED, __HIP_MEMORY_SCOPE_AGENT);
        int guard = 0;
        while ((unsigned)(v >> 32) != (unsigned)(t + 1) && ++guard < (1 << 22)) {
          v = __hip_atomic_load(slot, __ATOMIC_RELAXED, __HIP_MEMORY_SCOPE_AGENT);
        }
        union { unsigned u; float f; } c; c.u = (unsigned)v;
        hbuf[tid] = c.f;
      }
      __syncthreads();
      float ar = 0.f, az = 0.f, an = 0.f;
#pragma unroll
      for (int q4 = 0; q4 < 4; ++q4) {
        float4 h4[4];
#pragma unroll
        for (int u = 0; u < 4; ++u) h4[u] = *(const float4*)&hbuf[kc * 64 + q4 * 16 + u * 4];
#pragma unroll
        for (int u = 0; u < 4; ++u) {
          const float hh[4] = {h4[u].x, h4[u].y, h4[u].z, h4[u].w};
#pragma unroll
          for (int v = 0; v < 4; ++v) {
            const int q = q4 * 16 + u * 4 + v;
            ar = fmaf(hh[v], wg[0][q], ar);
            az = fmaf(hh[v], wg[1][q], az);
            an = fmaf(hh[v], wg[2][q], an);
          }
        }
      }
      part[(0 * 8 + kc) * 64 + hl] = ar;
      part[(1 * 8 + kc) * 64 + hl] = az;
      part[(2 * 8 + kc) * 64 + hl] = an;
      __syncthreads();
      if (tid < 64) {
        float sr = bhr, sz = bhz, sn = bhn;
#pragma unroll
        for (int c = 0; c < 8; ++c) {
          sr += part[(0 * 8 + c) * 64 + tid];
          sz += part[(1 * 8 + c) * 64 + tid];
          sn += part[(2 * 8 + c) * 64 + tid];
        }
        float r = 1.f / (1.f + expf(-(gr + sr)));
        float z = 1.f / (1.f + expf(-(gz + sz)));
        float n = tanhf(gn + r * sn);
        float hp = hbuf[sub * 64 + tid];
        float hv = (1.f - z) * n + z * hp;
        if (t < NT - 1) {
          union { float f; unsigned u; } c2; c2.f = hv;
          unsigned long long out = ((unsigned long long)(unsigned)(t + 2) << 32) | c2.u;
          __hip_atomic_store(htag + ((long long)((t + 1) & 1) * NB + b) * 512 + sub * 64 + tid, out,
                             __ATOMIC_RELAXED, __HIP_MEMORY_SCOPE_AGENT);
        }
        __hip_atomic_store(&h_all[(long long)((t + 1) * 16 + b) * 512 + sub * 64 + tid], hv,
                           __ATOMIC_RELAXED, __HIP_MEMORY_SCOPE_AGENT);
        if (t == NT - 1) d_hf[b * 512 + sub * 64 + tid] = hv;
      }
      __syncthreads();
      if (tid == 0)
        __hip_atomic_fetch_add(&hdone[t * 16 + b], 1u, __ATOMIC_RELAXED, __HIP_MEMORY_SCOPE_AGENT);
    }
    return;
  }

  // ================= conv + attention + att_lin consumers (512 threads) =================
  const int cid = bid - 128;
  {
    long long n4 = (long long)NV * NH / 4;
    for (long long i = (long long)cid * 512 + tid; i < n4; i += (long long)128 * 512) {
      float4 v = ((const float4*)out_w)[i];
      union { __bf16 b[4]; float2 f2; } u;
      u.b[0] = (__bf16)v.x; u.b[1] = (__bf16)v.y; u.b[2] = (__bf16)v.z; u.b[3] = (__bf16)v.w;
      *((float2*)((__bf16*)owb + 4 * i)) = u.f2;
    }
  }
  float* hb = smem;            // [512]
  float* mixs = smem + 512;    // [512]
  float* red = smem + 1024;    // [512] (scores partials, then attended staging)
  float* wb = smem + 1536;     // [128]
  float* sred = smem + 1664;   // [2]
  const int lane = tid & 63;
  const int wav = tid >> 6;    // 0..7
  for (int it = 0; it < 16; ++it) {
    const int u = it * 128 + cid;
    const int t = u >> 4, b = u & 15;
    if (tid == 0) {
      int guard = 0;
      while (__hip_atomic_load(&hdone[u], __ATOMIC_RELAXED, __HIP_MEMORY_SCOPE_AGENT) < 8u &&
             ++guard < (1 << 25)) {
        __builtin_amdgcn_s_sleep(4);
      }
    }
    __syncthreads();
    hb[tid] = __hip_atomic_load(&h_all[(long long)((t + 1) * 16 + b) * 512 + tid],
                                __ATOMIC_RELAXED, __HIP_MEMORY_SCOPE_AGENT);
    __syncthreads();
    // scores
    {
      const int s = tid & 127, q = tid >> 7;
      const float* erow = enc + (long long)(b * 128 + s) * 512 + q * 128;
      float p = 0.f;
#pragma unroll 8
      for (int k = 0; k < 128; ++k) p = fmaf(hb[q * 128 + k], erow[k], p);
      red[tid] = p;
    }
    __syncthreads();
    float sc = 0.f;
    if (tid < 128) {
      sc = red[tid] + red[tid + 128] + red[tid + 256] + red[tid + 384];
      if (mask[b * 128 + tid] == 0) sc = -1e6f;
      wb[tid] = sc;
    }
    __syncthreads();
    if (tid < 64) {
      float m2 = fmaxf(wb[tid], wb[tid + 64]);
      for (int off = 32; off; off >>= 1) m2 = fmaxf(m2, __shfl_down(m2, off));
      if (tid == 0) sred[0] = m2;
    }
    __syncthreads();
    if (tid < 128) wb[tid] = expf(sc - sred[0]);
    __syncthreads();
    if (tid < 64) {
      float s2 = wb[tid] + wb[tid + 64];
      for (int off = 32; off; off >>= 1) s2 += __shfl_down(s2, off);
      if (tid == 0) sred[1] = s2;
    }
    __syncthreads();
    {
      float inv = 1.f / sred[1];
      if (tid < 128) {
        float w = wb[tid] * inv;
        wb[tid] = w;
        d_attn[(long long)u * 128 + tid] = w;
      }
    }
    __syncthreads();
    // mix into LDS
    {
      float m = 0.f;
#pragma unroll 8
      for (int s2 = 0; s2 < 128; ++s2)
        m = fmaf(wb[s2], enc[(long long)(b * 128 + s2) * 512 + tid], m);
      mixs[tid] = m;
    }
    __syncthreads();
    // att_lin: wave-cooperative, COALESCED lwb reads.
    // wave wav computes outputs o = wav*64 + oi. lane l holds comb[k], k in [l*16, l*16+16).
    {
      float cv[16];
      const float* csrc = (lane < 32) ? &hb[lane * 16] : &mixs[(lane - 32) * 16];
#pragma unroll
      for (int jj = 0; jj < 16; ++jj) cv[jj] = csrc[jj];
      for (int oi = 0; oi < 64; ++oi) {
        const int o = wav * 64 + oi;
        const unsigned short* wrow = lwb + (long long)o * 1024 + lane * 16;
        uint4 wa = *(const uint4*)wrow;         // k .. k+7
        uint4 wc = *(const uint4*)(wrow + 8);   // k+8 .. k+15
        float p = 0.f;
        p = fmaf(cv[0],  bits2f(wa.x << 16), p);
        p = fmaf(cv[1],  bits2f(wa.x & 0xffff0000u), p);
        p = fmaf(cv[2],  bits2f(wa.y << 16), p);
        p = fmaf(cv[3],  bits2f(wa.y & 0xffff0000u), p);
        p = fmaf(cv[4],  bits2f(wa.z << 16), p);
        p = fmaf(cv[5],  bits2f(wa.z & 0xffff0000u), p);
        p = fmaf(cv[6],  bits2f(wa.w << 16), p);
        p = fmaf(cv[7],  bits2f(wa.w & 0xffff0000u), p);
        p = fmaf(cv[8],  bits2f(wc.x << 16), p);
        p = fmaf(cv[9],  bits2f(wc.x & 0xffff0000u), p);
        p = fmaf(cv[10], bits2f(wc.y << 16), p);
        p = fmaf(cv[11], bits2f(wc.y & 0xffff0000u), p);
        p = fmaf(cv[12], bits2f(wc.z << 16), p);
        p = fmaf(cv[13], bits2f(wc.z & 0xffff0000u), p);
        p = fmaf(cv[14], bits2f(wc.w << 16), p);
        p = fmaf(cv[15], bits2f(wc.w & 0xffff0000u), p);
#pragma unroll
        for (int off = 32; off; off >>= 1) p += __shfl_xor(p, off, 64);
        if (lane == 0) red[o] = p;   // full sum in all lanes; lane 0 stashes
      }
    }
    __syncthreads();
    // coalesced attended write
    attb[(long long)(b * 128 + t) * 512 + tid] = (__bf16)tanhf(red[tid]);
    __syncthreads();
  }
}

// ---------------- K3: scores = attended @ out_w^T + out_b  (bf16 MFMA, f32 out) ----------------
__global__ __launch_bounds__(256) void k_out(const __bf16* __restrict__ Abf,
                                             const __bf16* __restrict__ Bbf,
                                             const float* __restrict__ bias,
                                             float* __restrict__ Cout) {
  __shared__ __bf16 Al[128 * 32];
  __shared__ __bf16 Bl[128 * 32];
  const int tid = threadIdx.x;
  const int lane = tid & 63;
  const int wave = tid >> 6;
  const int wm = wave >> 1, wn = wave & 1;
  const int swz = (blockIdx.x & 7) * 500 + (blockIdx.x >> 3);
  const int m0 = (swz & 15) * 128, n0 = (swz >> 4) * 128;
  f32x4 acc[4][4] = {};
  const int lrow = lane >> 2;
  const int lcol = (lane & 3) * 8;
  const int lm = lane & 15, lc = lane >> 4;
  for (int ks = 0; ks < 16; ++ks) {
    const int k0 = ks * 32;
    __syncthreads();
#pragma unroll
    for (int i = 0; i < 2; ++i) {
      int chunk = wave * 2 + i;
      int r = chunk * 16 + lrow;
      const __bf16* ga = Abf + (long long)(m0 + r) * NH + k0 + lcol;
      const __bf16* gb = Bbf + (long long)(n0 + r) * NH + k0 + lcol;
      __builtin_amdgcn_global_load_lds((gu32*)ga, (lu32*)((char*)Al + chunk * 1024), 16, 0, 0);
      __builtin_amdgcn_global_load_lds((gu32*)gb, (lu32*)((char*)Bl + chunk * 1024), 16, 0, 0);
    }
    __syncthreads();
    bf16x8 af[4], bfr[4];
#pragma unroll
    for (int i = 0; i < 4; ++i) af[i] = *(const bf16x8*)&Al[(wm * 64 + i * 16 + lm) * 32 + lc * 8];
#pragma unroll
    for (int j = 0; j < 4; ++j) bfr[j] = *(const bf16x8*)&Bl[(wn * 64 + j * 16 + lm) * 32 + lc * 8];
#pragma unroll
    for (int i = 0; i < 4; ++i)
#pragma unroll
      for (int j = 0; j < 4; ++j)
        acc[i][j] = __builtin_amdgcn_mfma_f32_16x16x32_bf16(bfr[j], af[i], acc[i][j], 0, 0, 0);
  }
  float4 bv[4];
#pragma unroll
  for (int j = 0; j < 4; ++j)
    bv[j] = *(const float4*)&bias[n0 + wn * 64 + j * 16 + lc * 4];
#pragma unroll
  for (int i = 0; i < 4; ++i) {
    long long rbase = (long long)(m0 + wm * 64 + i * 16 + lm) * NV;
#pragma unroll
    for (int j = 0; j < 4; ++j) {
      int c = n0 + wn * 64 + j * 16 + lc * 4;
      float4 o;
      o.x = acc[i][j][0] + bv[j].x;
      o.y = acc[i][j][1] + bv[j].y;
      o.z = acc[i][j][2] + bv[j].z;
      o.w = acc[i][j][3] + bv[j].w;
      *(float4*)&Cout[rbase + c] = o;
    }
  }
}

// ---------------- launch ----------------
extern "C" void kernel_launch(void* const* d_in, const int* in_sizes, int n_in,
                              void* d_out, int out_size, void* d_ws, size_t ws_size,
                              hipStream_t stream) {
  const int* tv = (const int*)d_in[0];
  const float* dh = (const float*)d_in[1];
  const float* enc = (const float*)d_in[2];
  const int* mask = (const int*)d_in[3];
  const float* emb = (const float*)d_in[4];
  const float* w_ih = (const float*)d_in[5];
  const float* w_hh = (const float*)d_in[6];
  const float* b_ih = (const float*)d_in[7];
  const float* b_hh = (const float*)d_in[8];
  const float* lin_w = (const float*)d_in[9];
  const float* out_w = (const float*)d_in[10];
  const float* out_b = (const float*)d_in[11];
  float* dout = (float*)d_out;
  char* ws = (char*)d_ws;
  if (ws_size < WS_NEED) return;

  unsigned long long* htag = (unsigned long long*)(ws + HTAG_OFF);
  unsigned int* hdone = (unsigned int*)(ws + HDONE_OFF);
  float* whhT = (float*)(ws + WHHT_OFF);
  float* gi_all = (float*)(ws + GI_OFF);
  float* h_all = (float*)(ws + HALL_OFF);
  unsigned short* lwb = (unsigned short*)(ws + LWB_OFF);
  __bf16* attb = (__bf16*)(ws + ATTB_OFF);
  __bf16* owb = (__bf16*)(ws + OWB_OFF);

  float* d_scores = dout;                                  // [B,T,V]
  float* d_hf = dout + (long long)NB * NT * NV;            // [1,B,H]
  float* d_attn = d_hf + NB * NH;                          // [T,B,S]

  k_pg<<<1024, 256, 0, stream>>>(tv, emb, w_ih, b_ih, gi_all,
                                 w_hh, dh, lin_w, whhT, h_all, lwb, htag, hdone);
  k_mid<<<256, 512, 0, stream>>>(whhT, gi_all, b_hh, h_all, htag, hdone, d_hf,
                                 enc, mask, out_w, owb, lwb, d_attn, attb);
  k_out<<<4000, 256, 0, stream>>>(attb, owb, out_b, d_scores);
}

// Round 18
// 539.311 us; speedup vs baseline: 1.6027x; 1.5335x over previous
//
#include <hip/hip_runtime.h>
#include <hip/hip_bf16.h>

#define NV 32000
#define NE 512
#define NH 512
#define NB 16
#define NT 128
#define NS 128

typedef __bf16 bf16x8 __attribute__((ext_vector_type(8)));
typedef float f32x4 __attribute__((ext_vector_type(4)));
typedef const __attribute__((address_space(1))) unsigned int gu32;
typedef __attribute__((address_space(3))) unsigned int lu32;

// ---------------- workspace layout (bytes) ----------------
static constexpr size_t HTAG_OFF  = 0;                                    // [2][16][512] u64
static constexpr size_t HDONE_OFF = HTAG_OFF + (size_t)2*NB*NH*8;         // [2048] u32
static constexpr size_t WHHT_OFF  = HDONE_OFF + 8192;                     // [512][1536] f32
static constexpr size_t GI_OFF    = WHHT_OFF + (size_t)3*NH*NH*4;         // [T][B][1536] f32
static constexpr size_t HALL_OFF  = GI_OFF + (size_t)NT*NB*3*NH*4;        // [T+1][B][512] f32
static constexpr size_t MIX_OFF   = HALL_OFF + (size_t)(NT+1)*NB*NH*4;    // [B*T][512] f32
static constexpr size_t ATTB_OFF  = MIX_OFF + (size_t)NB*NT*NH*4;         // [B*T][512] bf16
static constexpr size_t OWB_OFF   = ATTB_OFF + (size_t)NB*NT*NH*2;        // [V][512] bf16
static constexpr size_t WS_NEED   = OWB_OFF + (size_t)NV*NH*2;            // ~59.1 MB

// ---------------- K1: merged prep + gi ----------------
__global__ __launch_bounds__(256) void k_pg(const int* __restrict__ tv,
                                            const float* __restrict__ emb,
                                            const float* __restrict__ w_ih,
                                            const float* __restrict__ b_ih,
                                            float* __restrict__ gi_all,
                                            const float* __restrict__ w_hh,
                                            const float* __restrict__ dh,
                                            float* __restrict__ whhT,
                                            float* __restrict__ h_all,
                                            unsigned long long* __restrict__ htag,
                                            unsigned int* __restrict__ hdone) {
  const int g = blockIdx.x;
  const int tid = threadIdx.x;
  if (g >= 768) {
    long long i0 = (long long)(g - 768) * 256 + tid;
    long long stride = (long long)256 * 256;
    for (long long i = i0; i < (long long)3 * NH * NH; i += stride) {
      int k = (int)(i / (3 * NH)), j = (int)(i % (3 * NH));
      whhT[i] = w_hh[(long long)j * NH + k];
    }
    for (long long i = i0; i < NB * NH; i += stride) {
      float hv = dh[i];
      h_all[i] = hv;
      union { float f; unsigned u; } c; c.f = hv;
      htag[i] = (1ull << 32) | c.u;
      htag[NB * NH + i] = 0ull;
    }
    for (long long i = i0; i < 2048; i += stride) hdone[i] = 0u;
    return;
  }
  __shared__ float As[16][64];
  __shared__ float Bs[16][64];
  const int n0 = (g % 24) * 64;
  const int m0 = (g / 24) * 64;
  float acc[4][4] = {};
  const int rl = tid >> 2;
  const int kq = (tid & 3) * 4;
  const int tvr = tv[m0 + rl];
  const float* arow = emb + (long long)tvr * NE;
  const int tm = tid & 15, tn = tid >> 4;
  for (int k0 = 0; k0 < NE; k0 += 16) {
    __syncthreads();
    float4 av = make_float4(0.f, 0.f, 0.f, 0.f);
    if (tvr != 0) av = *(const float4*)(arow + k0 + kq);
    float4 bv = *(const float4*)(w_ih + (long long)(n0 + rl) * NE + k0 + kq);
    As[kq + 0][rl] = av.x; As[kq + 1][rl] = av.y; As[kq + 2][rl] = av.z; As[kq + 3][rl] = av.w;
    Bs[kq + 0][rl] = bv.x; Bs[kq + 1][rl] = bv.y; Bs[kq + 2][rl] = bv.z; Bs[kq + 3][rl] = bv.w;
    __syncthreads();
#pragma unroll
    for (int kk = 0; kk < 16; ++kk) {
      float4 a = *(const float4*)&As[kk][tm * 4];
      float4 b = *(const float4*)&Bs[kk][tn * 4];
      float ar[4] = {a.x, a.y, a.z, a.w}, br[4] = {b.x, b.y, b.z, b.w};
#pragma unroll
      for (int i = 0; i < 4; ++i)
#pragma unroll
        for (int j = 0; j < 4; ++j) acc[i][j] = fmaf(ar[i], br[j], acc[i][j]);
    }
  }
#pragma unroll
  for (int i = 0; i < 4; ++i) {
    int r = m0 + tm * 4 + i;
    long long gb = (long long)((r & 127) * 16 + (r >> 7)) * (3 * NH);
#pragma unroll
    for (int j = 0; j < 4; ++j) {
      int jg = n0 + tn * 4 + j;
      gi_all[gb + jg] = acc[i][j] + b_ih[jg];
    }
  }
}

// ---------------- K2: k_mid — rec (0..127) || conv+attn (128..255) ----------------
// 256 blocks x 512 threads; 84KB LDS -> 1 block/CU (CU-exclusive), no VGPR spill.
__global__ __launch_bounds__(512, 1) void k_mid(const float* __restrict__ whhT,
                                                const float* __restrict__ gi_all,
                                                const float* __restrict__ b_hh,
                                                float* __restrict__ h_all,
                                                unsigned long long* __restrict__ htag,
                                                unsigned int* __restrict__ hdone,
                                                float* __restrict__ d_hf,
                                                const float* __restrict__ enc,
                                                const int* __restrict__ mask,
                                                const float* __restrict__ out_w,
                                                __bf16* __restrict__ owb,
                                                float* __restrict__ d_attn,
                                                float* __restrict__ mixb) {
  __shared__ char smem_raw[86016];   // 84 KB fences to 1 block/CU
  float* smem = (float*)smem_raw;
  const int tid = threadIdx.x;
  const int bid = blockIdx.x;

  if (bid < 128) {
    const int b = bid & 15, sub = bid >> 4;
    const int hl = tid & 63, kc = tid >> 6;
    const int j = sub * 64 + hl;
    float* hbuf = smem;
    float* part = smem + 512;

    float wg[3][64];
#pragma unroll
    for (int g = 0; g < 3; ++g) {
      const float* wp = whhT + (long long)(kc * 64) * 1536 + g * 512 + j;
#pragma unroll
      for (int q = 0; q < 64; ++q) wg[g][q] = wp[(long long)q * 1536];
    }
    float bhr = 0.f, bhz = 0.f, bhn = 0.f;
    if (tid < 64) {
      bhr = b_hh[sub * 64 + tid];
      bhz = b_hh[512 + sub * 64 + tid];
      bhn = b_hh[1024 + sub * 64 + tid];
    }

    for (int t = 0; t < NT; ++t) {
      float gr = 0.f, gz = 0.f, gn = 0.f;
      if (tid < 64) {
        const float* gi = gi_all + (long long)(t * 16 + b) * 1536;
        gr = gi[sub * 64 + tid];
        gz = gi[512 + sub * 64 + tid];
        gn = gi[1024 + sub * 64 + tid];
      }
      {
        unsigned long long* slot = htag + ((long long)(t & 1) * NB + b) * 512 + tid;
        unsigned long long v = __hip_atomic_load(slot, __ATOMIC_RELAXED, __HIP_MEMORY_SCOPE_AGENT);
        int guard = 0;
        while ((unsigned)(v >> 32) != (unsigned)(t + 1) && ++guard < (1 << 22)) {
          v = __hip_atomic_load(slot, __ATOMIC_RELAXED, __HIP_MEMORY_SCOPE_AGENT);
        }
        union { unsigned u; float f; } c; c.u = (unsigned)v;
        hbuf[tid] = c.f;
      }
      __syncthreads();
      float ar = 0.f, az = 0.f, an = 0.f;
#pragma unroll
      for (int q4 = 0; q4 < 4; ++q4) {
        float4 h4[4];
#pragma unroll
        for (int u = 0; u < 4; ++u) h4[u] = *(const float4*)&hbuf[kc * 64 + q4 * 16 + u * 4];
#pragma unroll
        for (int u = 0; u < 4; ++u) {
          const float hh[4] = {h4[u].x, h4[u].y, h4[u].z, h4[u].w};
#pragma unroll
          for (int v = 0; v < 4; ++v) {
            const int q = q4 * 16 + u * 4 + v;
            ar = fmaf(hh[v], wg[0][q], ar);
            az = fmaf(hh[v], wg[1][q], az);
            an = fmaf(hh[v], wg[2][q], an);
          }
        }
      }
      part[(0 * 8 + kc) * 64 + hl] = ar;
      part[(1 * 8 + kc) * 64 + hl] = az;
      part[(2 * 8 + kc) * 64 + hl] = an;
      __syncthreads();
      if (tid < 64) {
        float sr = bhr, sz = bhz, sn = bhn;
#pragma unroll
        for (int c = 0; c < 8; ++c) {
          sr += part[(0 * 8 + c) * 64 + tid];
          sz += part[(1 * 8 + c) * 64 + tid];
          sn += part[(2 * 8 + c) * 64 + tid];
        }
        float r = 1.f / (1.f + expf(-(gr + sr)));
        float z = 1.f / (1.f + expf(-(gz + sz)));
        float n = tanhf(gn + r * sn);
        float hp = hbuf[sub * 64 + tid];
        float hv = (1.f - z) * n + z * hp;
        if (t < NT - 1) {
          union { float f; unsigned u; } c2; c2.f = hv;
          unsigned long long out = ((unsigned long long)(unsigned)(t + 2) << 32) | c2.u;
          __hip_atomic_store(htag + ((long long)((t + 1) & 1) * NB + b) * 512 + sub * 64 + tid, out,
                             __ATOMIC_RELAXED, __HIP_MEMORY_SCOPE_AGENT);
        }
        __hip_atomic_store(&h_all[(long long)((t + 1) * 16 + b) * 512 + sub * 64 + tid], hv,
                           __ATOMIC_RELAXED, __HIP_MEMORY_SCOPE_AGENT);
        if (t == NT - 1) d_hf[b * 512 + sub * 64 + tid] = hv;
      }
      __syncthreads();
      if (tid == 0)
        __hip_atomic_fetch_add(&hdone[t * 16 + b], 1u, __ATOMIC_RELAXED, __HIP_MEMORY_SCOPE_AGENT);
    }
    return;
  }

  // ================= conv + attention consumers (512 threads) =================
  const int cid = bid - 128;
  {
    long long n4 = (long long)NV * NH / 4;
    for (long long i = (long long)cid * 512 + tid; i < n4; i += (long long)128 * 512) {
      float4 v = ((const float4*)out_w)[i];
      union { __bf16 b[4]; float2 f2; } u;
      u.b[0] = (__bf16)v.x; u.b[1] = (__bf16)v.y; u.b[2] = (__bf16)v.z; u.b[3] = (__bf16)v.w;
      *((float2*)((__bf16*)owb + 4 * i)) = u.f2;
    }
  }
  float* hb = smem;            // [512]
  float* red = smem + 512;     // [512]
  float* wb = smem + 1024;     // [128]
  float* sred = smem + 1152;   // [2]
  for (int it = 0; it < 16; ++it) {
    const int u = it * 128 + cid;
    const int t = u >> 4, b = u & 15;
    if (tid == 0) {
      int guard = 0;
      while (__hip_atomic_load(&hdone[u], __ATOMIC_RELAXED, __HIP_MEMORY_SCOPE_AGENT) < 8u &&
             ++guard < (1 << 25)) {
        __builtin_amdgcn_s_sleep(4);
      }
    }
    __syncthreads();
    hb[tid] = __hip_atomic_load(&h_all[(long long)((t + 1) * 16 + b) * 512 + tid],
                                __ATOMIC_RELAXED, __HIP_MEMORY_SCOPE_AGENT);
    __syncthreads();
    {
      const int s = tid & 127, q = tid >> 7;
      const float* erow = enc + (long long)(b * 128 + s) * 512 + q * 128;
      float p = 0.f;
#pragma unroll 8
      for (int k = 0; k < 128; ++k) p = fmaf(hb[q * 128 + k], erow[k], p);
      red[tid] = p;
    }
    __syncthreads();
    float sc = 0.f;
    if (tid < 128) {
      sc = red[tid] + red[tid + 128] + red[tid + 256] + red[tid + 384];
      if (mask[b * 128 + tid] == 0) sc = -1e6f;
      wb[tid] = sc;
    }
    __syncthreads();
    if (tid < 64) {
      float m2 = fmaxf(wb[tid], wb[tid + 64]);
      for (int off = 32; off; off >>= 1) m2 = fmaxf(m2, __shfl_down(m2, off));
      if (tid == 0) sred[0] = m2;
    }
    __syncthreads();
    if (tid < 128) wb[tid] = expf(sc - sred[0]);
    __syncthreads();
    if (tid < 64) {
      float s2 = wb[tid] + wb[tid + 64];
      for (int off = 32; off; off >>= 1) s2 += __shfl_down(s2, off);
      if (tid == 0) sred[1] = s2;
    }
    __syncthreads();
    {
      float inv = 1.f / sred[1];
      if (tid < 128) {
        float w = wb[tid] * inv;
        wb[tid] = w;
        d_attn[(long long)u * 128 + tid] = w;
      }
    }
    __syncthreads();
    {
      float m = 0.f;
#pragma unroll 8
      for (int s2 = 0; s2 < 128; ++s2)
        m = fmaf(wb[s2], enc[(long long)(b * 128 + s2) * 512 + tid], m);
      mixb[(long long)(b * 128 + t) * 512 + tid] = m;
    }
    __syncthreads();
  }
}

// ---------------- K3: attended = tanh([h,mix] @ lin_out_w^T) -> bf16 ----------------
__global__ __launch_bounds__(256) void k_att_lin(const float* __restrict__ h_all,
                                                 const float* __restrict__ mix,
                                                 const float* __restrict__ W,
                                                 __bf16* __restrict__ attout) {
  __shared__ float As[16][64];
  __shared__ float Bs[16][64];
  const int tid = threadIdx.x;
  const int n0 = blockIdx.x * 64;
  const int m0 = blockIdx.y * 64;
  float acc[4][4] = {};
  const int rl = tid >> 2;
  const int kq = (tid & 3) * 4;
  const int tm = tid & 15, tn = tid >> 4;
  const int r_a = m0 + rl;
  const int b_a = r_a >> 7, t_a = r_a & 127;
  const float* hrow = h_all + (long long)((t_a + 1) * 16 + b_a) * 512;
  const float* mrow = mix + (long long)r_a * 512;
  for (int k0 = 0; k0 < 1024; k0 += 16) {
    __syncthreads();
    float4 av = (k0 < 512) ? *(const float4*)(hrow + k0 + kq)
                           : *(const float4*)(mrow + (k0 - 512) + kq);
    float4 bv = *(const float4*)(W + (long long)(n0 + rl) * 1024 + k0 + kq);
    As[kq + 0][rl] = av.x; As[kq + 1][rl] = av.y; As[kq + 2][rl] = av.z; As[kq + 3][rl] = av.w;
    Bs[kq + 0][rl] = bv.x; Bs[kq + 1][rl] = bv.y; Bs[kq + 2][rl] = bv.z; Bs[kq + 3][rl] = bv.w;
    __syncthreads();
#pragma unroll
    for (int kk = 0; kk < 16; ++kk) {
      float4 a = *(const float4*)&As[kk][tm * 4];
      float4 b = *(const float4*)&Bs[kk][tn * 4];
      float ar[4] = {a.x, a.y, a.z, a.w}, br[4] = {b.x, b.y, b.z, b.w};
#pragma unroll
      for (int i = 0; i < 4; ++i)
#pragma unroll
        for (int j = 0; j < 4; ++j) acc[i][j] = fmaf(ar[i], br[j], acc[i][j]);
    }
  }
#pragma unroll
  for (int i = 0; i < 4; ++i) {
    int r = m0 + tm * 4 + i;
#pragma unroll
    for (int j = 0; j < 4; ++j) {
      int o = n0 + tn * 4 + j;
      attout[(long long)r * 512 + o] = (__bf16)tanhf(acc[i][j]);
    }
  }
}

// ---------------- K4: scores = attended @ out_w^T + out_b  (bf16 MFMA, 128x256 tile) ----------------
// Swapped-operand MFMA -> float4 coalesced C stores. Grid 2000 (16 m x 125 n), bijective swizzle.
__global__ __launch_bounds__(256) void k_out(const __bf16* __restrict__ Abf,
                                             const __bf16* __restrict__ Bbf,
                                             const float* __restrict__ bias,
                                             float* __restrict__ Cout) {
  __shared__ __bf16 Al[128 * 32];   // 8 KB
  __shared__ __bf16 Bl[256 * 32];   // 16 KB
  const int tid = threadIdx.x;
  const int lane = tid & 63;
  const int wave = tid >> 6;
  const int wm = wave >> 1, wn = wave & 1;
  const int swz = (blockIdx.x & 7) * 250 + (blockIdx.x >> 3);   // 2000 % 8 == 0 -> bijective
  const int m0 = (swz & 15) * 128, n0 = (swz >> 4) * 256;
  f32x4 acc[4][8] = {};
  const int lrow = lane >> 2;
  const int lcol = (lane & 3) * 8;
  const int lm = lane & 15, lc = lane >> 4;
  for (int ks = 0; ks < 16; ++ks) {
    const int k0 = ks * 32;
    __syncthreads();
#pragma unroll
    for (int i = 0; i < 6; ++i) {
      int c = wave * 6 + i;     // 0..23: 8 A-chunks then 16 B-chunks
      if (c < 8) {
        int r = c * 16 + lrow;
        const __bf16* ga = Abf + (long long)(m0 + r) * NH + k0 + lcol;
        __builtin_amdgcn_global_load_lds((gu32*)ga, (lu32*)((char*)Al + c * 1024), 16, 0, 0);
      } else {
        int cb = c - 8;
        int r = cb * 16 + lrow;
        const __bf16* gb = Bbf + (long long)(n0 + r) * NH + k0 + lcol;
        __builtin_amdgcn_global_load_lds((gu32*)gb, (lu32*)((char*)Bl + cb * 1024), 16, 0, 0);
      }
    }
    __syncthreads();
    bf16x8 af[4], bfr[8];
#pragma unroll
    for (int i = 0; i < 4; ++i) af[i] = *(const bf16x8*)&Al[(wm * 64 + i * 16 + lm) * 32 + lc * 8];
#pragma unroll
    for (int j = 0; j < 8; ++j) bfr[j] = *(const bf16x8*)&Bl[(wn * 128 + j * 16 + lm) * 32 + lc * 8];
#pragma unroll
    for (int i = 0; i < 4; ++i)
#pragma unroll
      for (int j = 0; j < 8; ++j)
        acc[i][j] = __builtin_amdgcn_mfma_f32_16x16x32_bf16(bfr[j], af[i], acc[i][j], 0, 0, 0);
  }
  float4 bv[8];
#pragma unroll
  for (int j = 0; j < 8; ++j)
    bv[j] = *(const float4*)&bias[n0 + wn * 128 + j * 16 + lc * 4];
#pragma unroll
  for (int i = 0; i < 4; ++i) {
    long long rbase = (long long)(m0 + wm * 64 + i * 16 + lm) * NV;
#pragma unroll
    for (int j = 0; j < 8; ++j) {
      int c = n0 + wn * 128 + j * 16 + lc * 4;
      float4 o;
      o.x = acc[i][j][0] + bv[j].x;
      o.y = acc[i][j][1] + bv[j].y;
      o.z = acc[i][j][2] + bv[j].z;
      o.w = acc[i][j][3] + bv[j].w;
      *(float4*)&Cout[rbase + c] = o;
    }
  }
}

// ---------------- launch ----------------
extern "C" void kernel_launch(void* const* d_in, const int* in_sizes, int n_in,
                              void* d_out, int out_size, void* d_ws, size_t ws_size,
                              hipStream_t stream) {
  const int* tv = (const int*)d_in[0];
  const float* dh = (const float*)d_in[1];
  const float* enc = (const float*)d_in[2];
  const int* mask = (const int*)d_in[3];
  const float* emb = (const float*)d_in[4];
  const float* w_ih = (const float*)d_in[5];
  const float* w_hh = (const float*)d_in[6];
  const float* b_ih = (const float*)d_in[7];
  const float* b_hh = (const float*)d_in[8];
  const float* lin_w = (const float*)d_in[9];
  const float* out_w = (const float*)d_in[10];
  const float* out_b = (const float*)d_in[11];
  float* dout = (float*)d_out;
  char* ws = (char*)d_ws;
  if (ws_size < WS_NEED) return;

  unsigned long long* htag = (unsigned long long*)(ws + HTAG_OFF);
  unsigned int* hdone = (unsigned int*)(ws + HDONE_OFF);
  float* whhT = (float*)(ws + WHHT_OFF);
  float* gi_all = (float*)(ws + GI_OFF);
  float* h_all = (float*)(ws + HALL_OFF);
  float* mixb = (float*)(ws + MIX_OFF);
  __bf16* attb = (__bf16*)(ws + ATTB_OFF);
  __bf16* owb = (__bf16*)(ws + OWB_OFF);

  float* d_scores = dout;                                  // [B,T,V]
  float* d_hf = dout + (long long)NB * NT * NV;            // [1,B,H]
  float* d_attn = d_hf + NB * NH;                          // [T,B,S]

  k_pg<<<1024, 256, 0, stream>>>(tv, emb, w_ih, b_ih, gi_all,
                                 w_hh, dh, whhT, h_all, htag, hdone);
  k_mid<<<256, 512, 0, stream>>>(whhT, gi_all, b_hh, h_all, htag, hdone, d_hf,
                                 enc, mask, out_w, owb, d_attn, mixb);
  k_att_lin<<<dim3(8, 32), 256, 0, stream>>>(h_all, mixb, lin_w, attb);
  k_out<<<2000, 256, 0, stream>>>(attb, owb, out_b, d_scores);
}

// Round 19
// 499.844 us; speedup vs baseline: 1.7293x; 1.0790x over previous
//
#include <hip/hip_runtime.h>
#include <hip/hip_bf16.h>

#define NV 32000
#define NE 512
#define NH 512
#define NB 16
#define NT 128
#define NS 128

typedef __bf16 bf16x8 __attribute__((ext_vector_type(8)));
typedef float f32x4 __attribute__((ext_vector_type(4)));
typedef const __attribute__((address_space(1))) unsigned int gu32;
typedef __attribute__((address_space(3))) unsigned int lu32;

// ---------------- workspace layout (bytes) ----------------
static constexpr size_t HTAG_OFF  = 0;                                    // [2][16][512] u64
static constexpr size_t HDONE_OFF = HTAG_OFF + (size_t)2*NB*NH*8;         // [2048] u32
static constexpr size_t WHHT_OFF  = HDONE_OFF + 8192;                     // [512][1536] f32
static constexpr size_t GI_OFF    = WHHT_OFF + (size_t)3*NH*NH*4;         // [T][B][1536] f32
static constexpr size_t HALL_OFF  = GI_OFF + (size_t)NT*NB*3*NH*4;        // [T+1][B][512] f32
static constexpr size_t MIX_OFF   = HALL_OFF + (size_t)(NT+1)*NB*NH*4;    // [B*T][512] f32
static constexpr size_t ATTB_OFF  = MIX_OFF + (size_t)NB*NT*NH*4;         // [B*T][512] bf16
static constexpr size_t OWB_OFF   = ATTB_OFF + (size_t)NB*NT*NH*2;        // [V][512] bf16
static constexpr size_t WS_NEED   = OWB_OFF + (size_t)NV*NH*2;            // ~59.1 MB

// ---------------- K1: merged prep + gi ----------------
// blocks 0..767: gi GEMM; 768..959: tiled w_hh transpose; 960..1023: h0/htag/hdone init
__global__ __launch_bounds__(256) void k_pg(const int* __restrict__ tv,
                                            const float* __restrict__ emb,
                                            const float* __restrict__ w_ih,
                                            const float* __restrict__ b_ih,
                                            float* __restrict__ gi_all,
                                            const float* __restrict__ w_hh,
                                            const float* __restrict__ dh,
                                            float* __restrict__ whhT,
                                            float* __restrict__ h_all,
                                            unsigned long long* __restrict__ htag,
                                            unsigned int* __restrict__ hdone) {
  __shared__ float sbuf[4160];   // gi: As(1024)+Bs(1024); transpose: tile 64x65
  const int g = blockIdx.x;
  const int tid = threadIdx.x;
  if (g >= 960) {
    long long i0 = (long long)(g - 960) * 256 + tid;
    long long stride = (long long)64 * 256;
    for (long long i = i0; i < NB * NH; i += stride) {
      float hv = dh[i];
      h_all[i] = hv;
      union { float f; unsigned u; } c; c.f = hv;
      htag[i] = (1ull << 32) | c.u;
      htag[NB * NH + i] = 0ull;
    }
    for (long long i = i0; i < 2048; i += stride) hdone[i] = 0u;
    return;
  }
  if (g >= 768) {
    // tiled transpose: w_hh [1536][512] -> whhT [512][1536], both sides coalesced
    float (*tile)[65] = (float (*)[65])sbuf;
    const int gg = g - 768;                 // 0..191
    const int j0 = (gg >> 3) * 64;          // w_hh row tile (24)
    const int k0 = (gg & 7) * 64;           // w_hh col tile (8)
    const int c = tid & 63, rb = tid >> 6;  // 4 rows/pass
#pragma unroll
    for (int p = 0; p < 16; ++p) {
      int r = p * 4 + rb;
      tile[r][c] = w_hh[(long long)(j0 + r) * NH + k0 + c];
    }
    __syncthreads();
#pragma unroll
    for (int p = 0; p < 16; ++p) {
      int kk = p * 4 + rb;
      whhT[(long long)(k0 + kk) * 1536 + j0 + c] = tile[c][kk];
    }
    return;
  }
  // ---- gi part ----
  float (*As)[64] = (float (*)[64])sbuf;
  float (*Bs)[64] = (float (*)[64])(sbuf + 1024);
  const int n0 = (g % 24) * 64;
  const int m0 = (g / 24) * 64;
  float acc[4][4] = {};
  const int rl = tid >> 2;
  const int kq = (tid & 3) * 4;
  const int tvr = tv[m0 + rl];
  const float* arow = emb + (long long)tvr * NE;
  const int tm = tid & 15, tn = tid >> 4;
  for (int k0 = 0; k0 < NE; k0 += 16) {
    __syncthreads();
    float4 av = make_float4(0.f, 0.f, 0.f, 0.f);
    if (tvr != 0) av = *(const float4*)(arow + k0 + kq);
    float4 bv = *(const float4*)(w_ih + (long long)(n0 + rl) * NE + k0 + kq);
    As[kq + 0][rl] = av.x; As[kq + 1][rl] = av.y; As[kq + 2][rl] = av.z; As[kq + 3][rl] = av.w;
    Bs[kq + 0][rl] = bv.x; Bs[kq + 1][rl] = bv.y; Bs[kq + 2][rl] = bv.z; Bs[kq + 3][rl] = bv.w;
    __syncthreads();
#pragma unroll
    for (int kk = 0; kk < 16; ++kk) {
      float4 a = *(const float4*)&As[kk][tm * 4];
      float4 b = *(const float4*)&Bs[kk][tn * 4];
      float ar[4] = {a.x, a.y, a.z, a.w}, br[4] = {b.x, b.y, b.z, b.w};
#pragma unroll
      for (int i = 0; i < 4; ++i)
#pragma unroll
        for (int j = 0; j < 4; ++j) acc[i][j] = fmaf(ar[i], br[j], acc[i][j]);
    }
  }
#pragma unroll
  for (int i = 0; i < 4; ++i) {
    int r = m0 + tm * 4 + i;
    long long gb = (long long)((r & 127) * 16 + (r >> 7)) * (3 * NH);
#pragma unroll
    for (int j = 0; j < 4; ++j) {
      int jg = n0 + tn * 4 + j;
      gi_all[gb + jg] = acc[i][j] + b_ih[jg];
    }
  }
}

// ---------------- K2: k_mid — rec (0..127) || conv+attn (128..255) ----------------
// 256 blocks x 512 threads; 84KB LDS -> 1 block/CU (CU-exclusive), no VGPR spill.
__global__ __launch_bounds__(512, 1) void k_mid(const float* __restrict__ whhT,
                                                const float* __restrict__ gi_all,
                                                const float* __restrict__ b_hh,
                                                float* __restrict__ h_all,
                                                unsigned long long* __restrict__ htag,
                                                unsigned int* __restrict__ hdone,
                                                float* __restrict__ d_hf,
                                                const float* __restrict__ enc,
                                                const int* __restrict__ mask,
                                                const float* __restrict__ out_w,
                                                __bf16* __restrict__ owb,
                                                float* __restrict__ d_attn,
                                                float* __restrict__ mixb) {
  __shared__ char smem_raw[86016];   // 84 KB fences to 1 block/CU
  float* smem = (float*)smem_raw;
  const int tid = threadIdx.x;
  const int bid = blockIdx.x;

  if (bid < 128) {
    const int b = bid & 15, sub = bid >> 4;
    const int hl = tid & 63, kc = tid >> 6;
    const int j = sub * 64 + hl;
    float* hbuf = smem;
    float* part = smem + 512;

    float wg[3][64];
#pragma unroll
    for (int g = 0; g < 3; ++g) {
      const float* wp = whhT + (long long)(kc * 64) * 1536 + g * 512 + j;
#pragma unroll
      for (int q = 0; q < 64; ++q) wg[g][q] = wp[(long long)q * 1536];
    }
    float bhr = 0.f, bhz = 0.f, bhn = 0.f;
    if (tid < 64) {
      bhr = b_hh[sub * 64 + tid];
      bhz = b_hh[512 + sub * 64 + tid];
      bhn = b_hh[1024 + sub * 64 + tid];
    }

    for (int t = 0; t < NT; ++t) {
      float gr = 0.f, gz = 0.f, gn = 0.f;
      if (tid < 64) {
        const float* gi = gi_all + (long long)(t * 16 + b) * 1536;
        gr = gi[sub * 64 + tid];
        gz = gi[512 + sub * 64 + tid];
        gn = gi[1024 + sub * 64 + tid];
      }
      {
        unsigned long long* slot = htag + ((long long)(t & 1) * NB + b) * 512 + tid;
        unsigned long long v = __hip_atomic_load(slot, __ATOMIC_RELAXED, __HIP_MEMORY_SCOPE_AGENT);
        int guard = 0;
        while ((unsigned)(v >> 32) != (unsigned)(t + 1) && ++guard < (1 << 22)) {
          v = __hip_atomic_load(slot, __ATOMIC_RELAXED, __HIP_MEMORY_SCOPE_AGENT);
        }
        union { unsigned u; float f; } c; c.u = (unsigned)v;
        hbuf[tid] = c.f;
      }
      __syncthreads();
      float ar = 0.f, az = 0.f, an = 0.f;
#pragma unroll
      for (int q4 = 0; q4 < 4; ++q4) {
        float4 h4[4];
#pragma unroll
        for (int u = 0; u < 4; ++u) h4[u] = *(const float4*)&hbuf[kc * 64 + q4 * 16 + u * 4];
#pragma unroll
        for (int u = 0; u < 4; ++u) {
          const float hh[4] = {h4[u].x, h4[u].y, h4[u].z, h4[u].w};
#pragma unroll
          for (int v = 0; v < 4; ++v) {
            const int q = q4 * 16 + u * 4 + v;
            ar = fmaf(hh[v], wg[0][q], ar);
            az = fmaf(hh[v], wg[1][q], az);
            an = fmaf(hh[v], wg[2][q], an);
          }
        }
      }
      part[(0 * 8 + kc) * 64 + hl] = ar;
      part[(1 * 8 + kc) * 64 + hl] = az;
      part[(2 * 8 + kc) * 64 + hl] = an;
      __syncthreads();
      if (tid < 64) {
        float sr = bhr, sz = bhz, sn = bhn;
#pragma unroll
        for (int c = 0; c < 8; ++c) {
          sr += part[(0 * 8 + c) * 64 + tid];
          sz += part[(1 * 8 + c) * 64 + tid];
          sn += part[(2 * 8 + c) * 64 + tid];
        }
        float r = 1.f / (1.f + expf(-(gr + sr)));
        float z = 1.f / (1.f + expf(-(gz + sz)));
        float n = tanhf(gn + r * sn);
        float hp = hbuf[sub * 64 + tid];
        float hv = (1.f - z) * n + z * hp;
        if (t < NT - 1) {
          union { float f; unsigned u; } c2; c2.f = hv;
          unsigned long long out = ((unsigned long long)(unsigned)(t + 2) << 32) | c2.u;
          __hip_atomic_store(htag + ((long long)((t + 1) & 1) * NB + b) * 512 + sub * 64 + tid, out,
                             __ATOMIC_RELAXED, __HIP_MEMORY_SCOPE_AGENT);
        }
        __hip_atomic_store(&h_all[(long long)((t + 1) * 16 + b) * 512 + sub * 64 + tid], hv,
                           __ATOMIC_RELAXED, __HIP_MEMORY_SCOPE_AGENT);
        if (t == NT - 1) d_hf[b * 512 + sub * 64 + tid] = hv;
      }
      __syncthreads();
      if (tid == 0)
        __hip_atomic_fetch_add(&hdone[t * 16 + b], 1u, __ATOMIC_RELAXED, __HIP_MEMORY_SCOPE_AGENT);
    }
    return;
  }

  // ================= conv + attention consumers (512 threads) =================
  const int cid = bid - 128;
  {
    long long n4 = (long long)NV * NH / 4;
    for (long long i = (long long)cid * 512 + tid; i < n4; i += (long long)128 * 512) {
      float4 v = ((const float4*)out_w)[i];
      union { __bf16 b[4]; float2 f2; } u;
      u.b[0] = (__bf16)v.x; u.b[1] = (__bf16)v.y; u.b[2] = (__bf16)v.z; u.b[3] = (__bf16)v.w;
      *((float2*)((__bf16*)owb + 4 * i)) = u.f2;
    }
  }
  float* hb = smem;            // [512]
  float* red = smem + 512;     // [512]
  float* wb = smem + 1024;     // [128]
  float* sred = smem + 1152;   // [2]
  for (int it = 0; it < 16; ++it) {
    const int u = it * 128 + cid;
    const int t = u >> 4, b = u & 15;
    if (tid == 0) {
      int guard = 0;
      while (__hip_atomic_load(&hdone[u], __ATOMIC_RELAXED, __HIP_MEMORY_SCOPE_AGENT) < 8u &&
             ++guard < (1 << 25)) {
        __builtin_amdgcn_s_sleep(4);
      }
    }
    __syncthreads();
    hb[tid] = __hip_atomic_load(&h_all[(long long)((t + 1) * 16 + b) * 512 + tid],
                                __ATOMIC_RELAXED, __HIP_MEMORY_SCOPE_AGENT);
    __syncthreads();
    {
      const int s = tid & 127, q = tid >> 7;
      const float* erow = enc + (long long)(b * 128 + s) * 512 + q * 128;
      float p = 0.f;
#pragma unroll 8
      for (int k = 0; k < 128; ++k) p = fmaf(hb[q * 128 + k], erow[k], p);
      red[tid] = p;
    }
    __syncthreads();
    float sc = 0.f;
    if (tid < 128) {
      sc = red[tid] + red[tid + 128] + red[tid + 256] + red[tid + 384];
      if (mask[b * 128 + tid] == 0) sc = -1e6f;
      wb[tid] = sc;
    }
    __syncthreads();
    if (tid < 64) {
      float m2 = fmaxf(wb[tid], wb[tid + 64]);
      for (int off = 32; off; off >>= 1) m2 = fmaxf(m2, __shfl_down(m2, off));
      if (tid == 0) sred[0] = m2;
    }
    __syncthreads();
    if (tid < 128) wb[tid] = expf(sc - sred[0]);
    __syncthreads();
    if (tid < 64) {
      float s2 = wb[tid] + wb[tid + 64];
      for (int off = 32; off; off >>= 1) s2 += __shfl_down(s2, off);
      if (tid == 0) sred[1] = s2;
    }
    __syncthreads();
    {
      float inv = 1.f / sred[1];
      if (tid < 128) {
        float w = wb[tid] * inv;
        wb[tid] = w;
        d_attn[(long long)u * 128 + tid] = w;
      }
    }
    __syncthreads();
    {
      float m = 0.f;
#pragma unroll 8
      for (int s2 = 0; s2 < 128; ++s2)
        m = fmaf(wb[s2], enc[(long long)(b * 128 + s2) * 512 + tid], m);
      mixb[(long long)(b * 128 + t) * 512 + tid] = m;
    }
    __syncthreads();
  }
}

// ---------------- K3: attended = tanh([h,mix] @ lin_out_w^T) -> bf16 ----------------
__global__ __launch_bounds__(256) void k_att_lin(const float* __restrict__ h_all,
                                                 const float* __restrict__ mix,
                                                 const float* __restrict__ W,
                                                 __bf16* __restrict__ attout) {
  __shared__ float As[16][64];
  __shared__ float Bs[16][64];
  const int tid = threadIdx.x;
  const int n0 = blockIdx.x * 64;
  const int m0 = blockIdx.y * 64;
  float acc[4][4] = {};
  const int rl = tid >> 2;
  const int kq = (tid & 3) * 4;
  const int tm = tid & 15, tn = tid >> 4;
  const int r_a = m0 + rl;
  const int b_a = r_a >> 7, t_a = r_a & 127;
  const float* hrow = h_all + (long long)((t_a + 1) * 16 + b_a) * 512;
  const float* mrow = mix + (long long)r_a * 512;
  for (int k0 = 0; k0 < 1024; k0 += 16) {
    __syncthreads();
    float4 av = (k0 < 512) ? *(const float4*)(hrow + k0 + kq)
                           : *(const float4*)(mrow + (k0 - 512) + kq);
    float4 bv = *(const float4*)(W + (long long)(n0 + rl) * 1024 + k0 + kq);
    As[kq + 0][rl] = av.x; As[kq + 1][rl] = av.y; As[kq + 2][rl] = av.z; As[kq + 3][rl] = av.w;
    Bs[kq + 0][rl] = bv.x; Bs[kq + 1][rl] = bv.y; Bs[kq + 2][rl] = bv.z; Bs[kq + 3][rl] = bv.w;
    __syncthreads();
#pragma unroll
    for (int kk = 0; kk < 16; ++kk) {
      float4 a = *(const float4*)&As[kk][tm * 4];
      float4 b = *(const float4*)&Bs[kk][tn * 4];
      float ar[4] = {a.x, a.y, a.z, a.w}, br[4] = {b.x, b.y, b.z, b.w};
#pragma unroll
      for (int i = 0; i < 4; ++i)
#pragma unroll
        for (int j = 0; j < 4; ++j) acc[i][j] = fmaf(ar[i], br[j], acc[i][j]);
    }
  }
#pragma unroll
  for (int i = 0; i < 4; ++i) {
    int r = m0 + tm * 4 + i;
#pragma unroll
    for (int j = 0; j < 4; ++j) {
      int o = n0 + tn * 4 + j;
      attout[(long long)r * 512 + o] = (__bf16)tanhf(acc[i][j]);
    }
  }
}

// ---------------- K4: scores = attended @ out_w^T + out_b  (bf16 MFMA, 128x128, f32 out) ----------------
__global__ __launch_bounds__(256) void k_out(const __bf16* __restrict__ Abf,
                                             const __bf16* __restrict__ Bbf,
                                             const float* __restrict__ bias,
                                             float* __restrict__ Cout) {
  __shared__ __bf16 Al[128 * 32];
  __shared__ __bf16 Bl[128 * 32];
  const int tid = threadIdx.x;
  const int lane = tid & 63;
  const int wave = tid >> 6;
  const int wm = wave >> 1, wn = wave & 1;
  const int swz = (blockIdx.x & 7) * 500 + (blockIdx.x >> 3);   // bijective (4000 % 8 == 0)
  const int m0 = (swz & 15) * 128, n0 = (swz >> 4) * 128;
  f32x4 acc[4][4] = {};
  const int lrow = lane >> 2;
  const int lcol = (lane & 3) * 8;
  const int lm = lane & 15, lc = lane >> 4;
  for (int ks = 0; ks < 16; ++ks) {
    const int k0 = ks * 32;
    __syncthreads();
#pragma unroll
    for (int i = 0; i < 2; ++i) {
      int chunk = wave * 2 + i;
      int r = chunk * 16 + lrow;
      const __bf16* ga = Abf + (long long)(m0 + r) * NH + k0 + lcol;
      const __bf16* gb = Bbf + (long long)(n0 + r) * NH + k0 + lcol;
      __builtin_amdgcn_global_load_lds((gu32*)ga, (lu32*)((char*)Al + chunk * 1024), 16, 0, 0);
      __builtin_amdgcn_global_load_lds((gu32*)gb, (lu32*)((char*)Bl + chunk * 1024), 16, 0, 0);
    }
    __syncthreads();
    bf16x8 af[4], bfr[4];
#pragma unroll
    for (int i = 0; i < 4; ++i) af[i] = *(const bf16x8*)&Al[(wm * 64 + i * 16 + lm) * 32 + lc * 8];
#pragma unroll
    for (int j = 0; j < 4; ++j) bfr[j] = *(const bf16x8*)&Bl[(wn * 64 + j * 16 + lm) * 32 + lc * 8];
#pragma unroll
    for (int i = 0; i < 4; ++i)
#pragma unroll
      for (int j = 0; j < 4; ++j)
        acc[i][j] = __builtin_amdgcn_mfma_f32_16x16x32_bf16(bfr[j], af[i], acc[i][j], 0, 0, 0);
  }
  float4 bv[4];
#pragma unroll
  for (int j = 0; j < 4; ++j)
    bv[j] = *(const float4*)&bias[n0 + wn * 64 + j * 16 + lc * 4];
#pragma unroll
  for (int i = 0; i < 4; ++i) {
    long long rbase = (long long)(m0 + wm * 64 + i * 16 + lm) * NV;
#pragma unroll
    for (int j = 0; j < 4; ++j) {
      int c = n0 + wn * 64 + j * 16 + lc * 4;
      float4 o;
      o.x = acc[i][j][0] + bv[j].x;
      o.y = acc[i][j][1] + bv[j].y;
      o.z = acc[i][j][2] + bv[j].z;
      o.w = acc[i][j][3] + bv[j].w;
      *(float4*)&Cout[rbase + c] = o;
    }
  }
}

// ---------------- launch ----------------
extern "C" void kernel_launch(void* const* d_in, const int* in_sizes, int n_in,
                              void* d_out, int out_size, void* d_ws, size_t ws_size,
                              hipStream_t stream) {
  const int* tv = (const int*)d_in[0];
  const float* dh = (const float*)d_in[1];
  const float* enc = (const float*)d_in[2];
  const int* mask = (const int*)d_in[3];
  const float* emb = (const float*)d_in[4];
  const float* w_ih = (const float*)d_in[5];
  const float* w_hh = (const float*)d_in[6];
  const float* b_ih = (const float*)d_in[7];
  const float* b_hh = (const float*)d_in[8];
  const float* lin_w = (const float*)d_in[9];
  const float* out_w = (const float*)d_in[10];
  const float* out_b = (const float*)d_in[11];
  float* dout = (float*)d_out;
  char* ws = (char*)d_ws;
  if (ws_size < WS_NEED) return;

  unsigned long long* htag = (unsigned long long*)(ws + HTAG_OFF);
  unsigned int* hdone = (unsigned int*)(ws + HDONE_OFF);
  float* whhT = (float*)(ws + WHHT_OFF);
  float* gi_all = (float*)(ws + GI_OFF);
  float* h_all = (float*)(ws + HALL_OFF);
  float* mixb = (float*)(ws + MIX_OFF);
  __bf16* attb = (__bf16*)(ws + ATTB_OFF);
  __bf16* owb = (__bf16*)(ws + OWB_OFF);

  float* d_scores = dout;                                  // [B,T,V]
  float* d_hf = dout + (long long)NB * NT * NV;            // [1,B,H]
  float* d_attn = d_hf + NB * NH;                          // [T,B,S]

  k_pg<<<1024, 256, 0, stream>>>(tv, emb, w_ih, b_ih, gi_all,
                                 w_hh, dh, whhT, h_all, htag, hdone);
  k_mid<<<256, 512, 0, stream>>>(whhT, gi_all, b_hh, h_all, htag, hdone, d_hf,
                                 enc, mask, out_w, owb, d_attn, mixb);
  k_att_lin<<<dim3(8, 32), 256, 0, stream>>>(h_all, mixb, lin_w, attb);
  k_out<<<4000, 256, 0, stream>>>(attb, owb, out_b, d_scores);
}

// Round 20
// 495.821 us; speedup vs baseline: 1.7433x; 1.0081x over previous
//
#include <hip/hip_runtime.h>
#include <hip/hip_bf16.h>

#define NV 32000
#define NE 512
#define NH 512
#define NB 16
#define NT 128
#define NS 128

typedef __bf16 bf16x8 __attribute__((ext_vector_type(8)));
typedef float f32x4 __attribute__((ext_vector_type(4)));
typedef const __attribute__((address_space(1))) unsigned int gu32;
typedef __attribute__((address_space(3))) unsigned int lu32;

// ---------------- workspace layout (bytes) ----------------
static constexpr size_t HTAG_OFF  = 0;                                    // [2][16][512] u64
static constexpr size_t HDONE_OFF = HTAG_OFF + (size_t)2*NB*NH*8;         // [2048] u32
static constexpr size_t GI_OFF    = HDONE_OFF + 8192;                     // [T][B][1536] f32
static constexpr size_t HALL_OFF  = GI_OFF + (size_t)NT*NB*3*NH*4;        // [T+1][B][512] f32
static constexpr size_t MIX_OFF   = HALL_OFF + (size_t)(NT+1)*NB*NH*4;    // [B*T][512] f32
static constexpr size_t ATTB_OFF  = MIX_OFF + (size_t)NB*NT*NH*4;         // [B*T][512] bf16
static constexpr size_t OWB_OFF   = ATTB_OFF + (size_t)NB*NT*NH*2;        // [V][512] bf16
static constexpr size_t WS_NEED   = OWB_OFF + (size_t)NV*NH*2;            // ~56 MB

// ---------------- K1: merged prep + gi ----------------
// blocks 0..767: gi GEMM; 768..799: h0/htag/hdone init
__global__ __launch_bounds__(256) void k_pg(const int* __restrict__ tv,
                                            const float* __restrict__ emb,
                                            const float* __restrict__ w_ih,
                                            const float* __restrict__ b_ih,
                                            float* __restrict__ gi_all,
                                            const float* __restrict__ dh,
                                            float* __restrict__ h_all,
                                            unsigned long long* __restrict__ htag,
                                            unsigned int* __restrict__ hdone) {
  __shared__ float sbuf[2048];
  const int g = blockIdx.x;
  const int tid = threadIdx.x;
  if (g >= 768) {
    long long i0 = (long long)(g - 768) * 256 + tid;
    long long stride = (long long)32 * 256;
    for (long long i = i0; i < NB * NH; i += stride) {
      float hv = dh[i];
      h_all[i] = hv;
      union { float f; unsigned u; } c; c.f = hv;
      htag[i] = (1ull << 32) | c.u;
      htag[NB * NH + i] = 0ull;
    }
    for (long long i = i0; i < 2048; i += stride) hdone[i] = 0u;
    return;
  }
  // ---- gi part ----
  float (*As)[64] = (float (*)[64])sbuf;
  float (*Bs)[64] = (float (*)[64])(sbuf + 1024);
  const int n0 = (g % 24) * 64;
  const int m0 = (g / 24) * 64;
  float acc[4][4] = {};
  const int rl = tid >> 2;
  const int kq = (tid & 3) * 4;
  const int tvr = tv[m0 + rl];
  const float* arow = emb + (long long)tvr * NE;
  const int tm = tid & 15, tn = tid >> 4;
  for (int k0 = 0; k0 < NE; k0 += 16) {
    __syncthreads();
    float4 av = make_float4(0.f, 0.f, 0.f, 0.f);
    if (tvr != 0) av = *(const float4*)(arow + k0 + kq);
    float4 bv = *(const float4*)(w_ih + (long long)(n0 + rl) * NE + k0 + kq);
    As[kq + 0][rl] = av.x; As[kq + 1][rl] = av.y; As[kq + 2][rl] = av.z; As[kq + 3][rl] = av.w;
    Bs[kq + 0][rl] = bv.x; Bs[kq + 1][rl] = bv.y; Bs[kq + 2][rl] = bv.z; Bs[kq + 3][rl] = bv.w;
    __syncthreads();
#pragma unroll
    for (int kk = 0; kk < 16; ++kk) {
      float4 a = *(const float4*)&As[kk][tm * 4];
      float4 b = *(const float4*)&Bs[kk][tn * 4];
      float ar[4] = {a.x, a.y, a.z, a.w}, br[4] = {b.x, b.y, b.z, b.w};
#pragma unroll
      for (int i = 0; i < 4; ++i)
#pragma unroll
        for (int j = 0; j < 4; ++j) acc[i][j] = fmaf(ar[i], br[j], acc[i][j]);
    }
  }
#pragma unroll
  for (int i = 0; i < 4; ++i) {
    int r = m0 + tm * 4 + i;
    long long gb = (long long)((r & 127) * 16 + (r >> 7)) * (3 * NH);
#pragma unroll
    for (int j = 0; j < 4; ++j) {
      int jg = n0 + tn * 4 + j;
      gi_all[gb + jg] = acc[i][j] + b_ih[jg];
    }
  }
}

// ---------------- K2: k_mid — rec (0..127) || conv+attn (128..255) ----------------
// 256 blocks x 512 threads; 84KB LDS -> 1 block/CU (CU-exclusive), no VGPR spill.
__global__ __launch_bounds__(512, 1) void k_mid(const float* __restrict__ w_hh,
                                                const float* __restrict__ gi_all,
                                                const float* __restrict__ b_hh,
                                                float* __restrict__ h_all,
                                                unsigned long long* __restrict__ htag,
                                                unsigned int* __restrict__ hdone,
                                                float* __restrict__ d_hf,
                                                const float* __restrict__ enc,
                                                const int* __restrict__ mask,
                                                const float* __restrict__ out_w,
                                                __bf16* __restrict__ owb,
                                                float* __restrict__ d_attn,
                                                float* __restrict__ mixb) {
  __shared__ char smem_raw[86016];   // 84 KB fences to 1 block/CU
  float* smem = (float*)smem_raw;
  const int tid = threadIdx.x;
  const int bid = blockIdx.x;

  if (bid < 128) {
    const int b = bid & 15, sub = bid >> 4;
    const int hl = tid & 63, kc = tid >> 6;
    const int j = sub * 64 + hl;
    float* hbuf = smem;
    float* part = smem + 512;

    // direct contiguous preload: wg[g][q] = w_hh[(g*512+j)*512 + kc*64 + q]
    float wg[3][64];
#pragma unroll
    for (int g = 0; g < 3; ++g) {
      const float* wp = w_hh + (long long)(g * 512 + j) * NH + kc * 64;
#pragma unroll
      for (int q4 = 0; q4 < 16; ++q4) {
        float4 w4 = *(const float4*)(wp + q4 * 4);
        wg[g][q4 * 4 + 0] = w4.x; wg[g][q4 * 4 + 1] = w4.y;
        wg[g][q4 * 4 + 2] = w4.z; wg[g][q4 * 4 + 3] = w4.w;
      }
    }
    float bhr = 0.f, bhz = 0.f, bhn = 0.f;
    if (tid < 64) {
      bhr = b_hh[sub * 64 + tid];
      bhz = b_hh[512 + sub * 64 + tid];
      bhn = b_hh[1024 + sub * 64 + tid];
    }

    for (int t = 0; t < NT; ++t) {
      float gr = 0.f, gz = 0.f, gn = 0.f;
      if (tid < 64) {
        const float* gi = gi_all + (long long)(t * 16 + b) * 1536;
        gr = gi[sub * 64 + tid];
        gz = gi[512 + sub * 64 + tid];
        gn = gi[1024 + sub * 64 + tid];
      }
      {
        unsigned long long* slot = htag + ((long long)(t & 1) * NB + b) * 512 + tid;
        unsigned long long v = __hip_atomic_load(slot, __ATOMIC_RELAXED, __HIP_MEMORY_SCOPE_AGENT);
        int guard = 0;
        while ((unsigned)(v >> 32) != (unsigned)(t + 1) && ++guard < (1 << 22)) {
          v = __hip_atomic_load(slot, __ATOMIC_RELAXED, __HIP_MEMORY_SCOPE_AGENT);
        }
        union { unsigned u; float f; } c; c.u = (unsigned)v;
        hbuf[tid] = c.f;
      }
      __syncthreads();
      float ar = 0.f, az = 0.f, an = 0.f;
#pragma unroll
      for (int q4 = 0; q4 < 4; ++q4) {
        float4 h4[4];
#pragma unroll
        for (int u = 0; u < 4; ++u) h4[u] = *(const float4*)&hbuf[kc * 64 + q4 * 16 + u * 4];
#pragma unroll
        for (int u = 0; u < 4; ++u) {
          const float hh[4] = {h4[u].x, h4[u].y, h4[u].z, h4[u].w};
#pragma unroll
          for (int v = 0; v < 4; ++v) {
            const int q = q4 * 16 + u * 4 + v;
            ar = fmaf(hh[v], wg[0][q], ar);
            az = fmaf(hh[v], wg[1][q], az);
            an = fmaf(hh[v], wg[2][q], an);
          }
        }
      }
      part[(0 * 8 + kc) * 64 + hl] = ar;
      part[(1 * 8 + kc) * 64 + hl] = az;
      part[(2 * 8 + kc) * 64 + hl] = an;
      __syncthreads();
      if (tid < 64) {
        float sr = bhr, sz = bhz, sn = bhn;
#pragma unroll
        for (int c = 0; c < 8; ++c) {
          sr += part[(0 * 8 + c) * 64 + tid];
          sz += part[(1 * 8 + c) * 64 + tid];
          sn += part[(2 * 8 + c) * 64 + tid];
        }
        float r = 1.f / (1.f + expf(-(gr + sr)));
        float z = 1.f / (1.f + expf(-(gz + sz)));
        float n = tanhf(gn + r * sn);
        float hp = hbuf[sub * 64 + tid];
        float hv = (1.f - z) * n + z * hp;
        if (t < NT - 1) {
          union { float f; unsigned u; } c2; c2.f = hv;
          unsigned long long out = ((unsigned long long)(unsigned)(t + 2) << 32) | c2.u;
          __hip_atomic_store(htag + ((long long)((t + 1) & 1) * NB + b) * 512 + sub * 64 + tid, out,
                             __ATOMIC_RELAXED, __HIP_MEMORY_SCOPE_AGENT);
        }
        __hip_atomic_store(&h_all[(long long)((t + 1) * 16 + b) * 512 + sub * 64 + tid], hv,
                           __ATOMIC_RELAXED, __HIP_MEMORY_SCOPE_AGENT);
        if (t == NT - 1) d_hf[b * 512 + sub * 64 + tid] = hv;
      }
      __syncthreads();
      if (tid == 0)
        __hip_atomic_fetch_add(&hdone[t * 16 + b], 1u, __ATOMIC_RELAXED, __HIP_MEMORY_SCOPE_AGENT);
    }
    return;
  }

  // ================= conv + attention consumers (512 threads) =================
  const int cid = bid - 128;
  {
    long long n4 = (long long)NV * NH / 4;
    for (long long i = (long long)cid * 512 + tid; i < n4; i += (long long)128 * 512) {
      float4 v = ((const float4*)out_w)[i];
      union { __bf16 b[4]; float2 f2; } u;
      u.b[0] = (__bf16)v.x; u.b[1] = (__bf16)v.y; u.b[2] = (__bf16)v.z; u.b[3] = (__bf16)v.w;
      *((float2*)((__bf16*)owb + 4 * i)) = u.f2;
    }
  }
  float* hb = smem;            // [512]
  float* red = smem + 512;     // [512]
  float* wb = smem + 1024;     // [128]
  float* sred = smem + 1152;   // [2]
  for (int it = 0; it < 16; ++it) {
    const int u = it * 128 + cid;
    const int t = u >> 4, b = u & 15;
    if (tid == 0) {
      int guard = 0;
      while (__hip_atomic_load(&hdone[u], __ATOMIC_RELAXED, __HIP_MEMORY_SCOPE_AGENT) < 8u &&
             ++guard < (1 << 25)) {
        __builtin_amdgcn_s_sleep(4);
      }
    }
    __syncthreads();
    hb[tid] = __hip_atomic_load(&h_all[(long long)((t + 1) * 16 + b) * 512 + tid],
                                __ATOMIC_RELAXED, __HIP_MEMORY_SCOPE_AGENT);
    __syncthreads();
    {
      const int s = tid & 127, q = tid >> 7;
      const float* erow = enc + (long long)(b * 128 + s) * 512 + q * 128;
      float p = 0.f;
#pragma unroll 8
      for (int k = 0; k < 128; ++k) p = fmaf(hb[q * 128 + k], erow[k], p);
      red[tid] = p;
    }
    __syncthreads();
    float sc = 0.f;
    if (tid < 128) {
      sc = red[tid] + red[tid + 128] + red[tid + 256] + red[tid + 384];
      if (mask[b * 128 + tid] == 0) sc = -1e6f;
      wb[tid] = sc;
    }
    __syncthreads();
    if (tid < 64) {
      float m2 = fmaxf(wb[tid], wb[tid + 64]);
      for (int off = 32; off; off >>= 1) m2 = fmaxf(m2, __shfl_down(m2, off));
      if (tid == 0) sred[0] = m2;
    }
    __syncthreads();
    if (tid < 128) wb[tid] = expf(sc - sred[0]);
    __syncthreads();
    if (tid < 64) {
      float s2 = wb[tid] + wb[tid + 64];
      for (int off = 32; off; off >>= 1) s2 += __shfl_down(s2, off);
      if (tid == 0) sred[1] = s2;
    }
    __syncthreads();
    {
      float inv = 1.f / sred[1];
      if (tid < 128) {
        float w = wb[tid] * inv;
        wb[tid] = w;
        d_attn[(long long)u * 128 + tid] = w;
      }
    }
    __syncthreads();
    {
      float m = 0.f;
#pragma unroll 8
      for (int s2 = 0; s2 < 128; ++s2)
        m = fmaf(wb[s2], enc[(long long)(b * 128 + s2) * 512 + tid], m);
      mixb[(long long)(b * 128 + t) * 512 + tid] = m;
    }
    __syncthreads();
  }
}

// ---------------- K3: attended = tanh([h,mix] @ lin_out_w^T) -> bf16 ----------------
__global__ __launch_bounds__(256) void k_att_lin(const float* __restrict__ h_all,
                                                 const float* __restrict__ mix,
                                                 const float* __restrict__ W,
                                                 __bf16* __restrict__ attout) {
  __shared__ float As[16][64];
  __shared__ float Bs[16][64];
  const int tid = threadIdx.x;
  const int n0 = blockIdx.x * 64;
  const int m0 = blockIdx.y * 64;
  float acc[4][4] = {};
  const int rl = tid >> 2;
  const int kq = (tid & 3) * 4;
  const int tm = tid & 15, tn = tid >> 4;
  const int r_a = m0 + rl;
  const int b_a = r_a >> 7, t_a = r_a & 127;
  const float* hrow = h_all + (long long)((t_a + 1) * 16 + b_a) * 512;
  const float* mrow = mix + (long long)r_a * 512;
  for (int k0 = 0; k0 < 1024; k0 += 16) {
    __syncthreads();
    float4 av = (k0 < 512) ? *(const float4*)(hrow + k0 + kq)
                           : *(const float4*)(mrow + (k0 - 512) + kq);
    float4 bv = *(const float4*)(W + (long long)(n0 + rl) * 1024 + k0 + kq);
    As[kq + 0][rl] = av.x; As[kq + 1][rl] = av.y; As[kq + 2][rl] = av.z; As[kq + 3][rl] = av.w;
    Bs[kq + 0][rl] = bv.x; Bs[kq + 1][rl] = bv.y; Bs[kq + 2][rl] = bv.z; Bs[kq + 3][rl] = bv.w;
    __syncthreads();
#pragma unroll
    for (int kk = 0; kk < 16; ++kk) {
      float4 a = *(const float4*)&As[kk][tm * 4];
      float4 b = *(const float4*)&Bs[kk][tn * 4];
      float ar[4] = {a.x, a.y, a.z, a.w}, br[4] = {b.x, b.y, b.z, b.w};
#pragma unroll
      for (int i = 0; i < 4; ++i)
#pragma unroll
        for (int j = 0; j < 4; ++j) acc[i][j] = fmaf(ar[i], br[j], acc[i][j]);
    }
  }
#pragma unroll
  for (int i = 0; i < 4; ++i) {
    int r = m0 + tm * 4 + i;
#pragma unroll
    for (int j = 0; j < 4; ++j) {
      int o = n0 + tn * 4 + j;
      attout[(long long)r * 512 + o] = (__bf16)tanhf(acc[i][j]);
    }
  }
}

// ---------------- K4: scores = attended @ out_w^T + out_b  (bf16 MFMA, 128x128, f32 out) ----------------
__global__ __launch_bounds__(256) void k_out(const __bf16* __restrict__ Abf,
                                             const __bf16* __restrict__ Bbf,
                                             const float* __restrict__ bias,
                                             float* __restrict__ Cout) {
  __shared__ __bf16 Al[128 * 32];
  __shared__ __bf16 Bl[128 * 32];
  const int tid = threadIdx.x;
  const int lane = tid & 63;
  const int wave = tid >> 6;
  const int wm = wave >> 1, wn = wave & 1;
  const int swz = (blockIdx.x & 7) * 500 + (blockIdx.x >> 3);   // bijective (4000 % 8 == 0)
  const int m0 = (swz & 15) * 128, n0 = (swz >> 4) * 128;
  f32x4 acc[4][4] = {};
  const int lrow = lane >> 2;
  const int lcol = (lane & 3) * 8;
  const int lm = lane & 15, lc = lane >> 4;
  for (int ks = 0; ks < 16; ++ks) {
    const int k0 = ks * 32;
    __syncthreads();
#pragma unroll
    for (int i = 0; i < 2; ++i) {
      int chunk = wave * 2 + i;
      int r = chunk * 16 + lrow;
      const __bf16* ga = Abf + (long long)(m0 + r) * NH + k0 + lcol;
      const __bf16* gb = Bbf + (long long)(n0 + r) * NH + k0 + lcol;
      __builtin_amdgcn_global_load_lds((gu32*)ga, (lu32*)((char*)Al + chunk * 1024), 16, 0, 0);
      __builtin_amdgcn_global_load_lds((gu32*)gb, (lu32*)((char*)Bl + chunk * 1024), 16, 0, 0);
    }
    __syncthreads();
    bf16x8 af[4], bfr[4];
#pragma unroll
    for (int i = 0; i < 4; ++i) af[i] = *(const bf16x8*)&Al[(wm * 64 + i * 16 + lm) * 32 + lc * 8];
#pragma unroll
    for (int j = 0; j < 4; ++j) bfr[j] = *(const bf16x8*)&Bl[(wn * 64 + j * 16 + lm) * 32 + lc * 8];
#pragma unroll
    for (int i = 0; i < 4; ++i)
#pragma unroll
      for (int j = 0; j < 4; ++j)
        acc[i][j] = __builtin_amdgcn_mfma_f32_16x16x32_bf16(bfr[j], af[i], acc[i][j], 0, 0, 0);
  }
  float4 bv[4];
#pragma unroll
  for (int j = 0; j < 4; ++j)
    bv[j] = *(const float4*)&bias[n0 + wn * 64 + j * 16 + lc * 4];
#pragma unroll
  for (int i = 0; i < 4; ++i) {
    long long rbase = (long long)(m0 + wm * 64 + i * 16 + lm) * NV;
#pragma unroll
    for (int j = 0; j < 4; ++j) {
      int c = n0 + wn * 64 + j * 16 + lc * 4;
      float4 o;
      o.x = acc[i][j][0] + bv[j].x;
      o.y = acc[i][j][1] + bv[j].y;
      o.z = acc[i][j][2] + bv[j].z;
      o.w = acc[i][j][3] + bv[j].w;
      *(float4*)&Cout[rbase + c] = o;
    }
  }
}

// ---------------- launch ----------------
extern "C" void kernel_launch(void* const* d_in, const int* in_sizes, int n_in,
                              void* d_out, int out_size, void* d_ws, size_t ws_size,
                              hipStream_t stream) {
  const int* tv = (const int*)d_in[0];
  const float* dh = (const float*)d_in[1];
  const float* enc = (const float*)d_in[2];
  const int* mask = (const int*)d_in[3];
  const float* emb = (const float*)d_in[4];
  const float* w_ih = (const float*)d_in[5];
  const float* w_hh = (const float*)d_in[6];
  const float* b_ih = (const float*)d_in[7];
  const float* b_hh = (const float*)d_in[8];
  const float* lin_w = (const float*)d_in[9];
  const float* out_w = (const float*)d_in[10];
  const float* out_b = (const float*)d_in[11];
  float* dout = (float*)d_out;
  char* ws = (char*)d_ws;
  if (ws_size < WS_NEED) return;

  unsigned long long* htag = (unsigned long long*)(ws + HTAG_OFF);
  unsigned int* hdone = (unsigned int*)(ws + HDONE_OFF);
  float* gi_all = (float*)(ws + GI_OFF);
  float* h_all = (float*)(ws + HALL_OFF);
  float* mixb = (float*)(ws + MIX_OFF);
  __bf16* attb = (__bf16*)(ws + ATTB_OFF);
  __bf16* owb = (__bf16*)(ws + OWB_OFF);

  float* d_scores = dout;                                  // [B,T,V]
  float* d_hf = dout + (long long)NB * NT * NV;            // [1,B,H]
  float* d_attn = d_hf + NB * NH;                          // [T,B,S]

  k_pg<<<800, 256, 0, stream>>>(tv, emb, w_ih, b_ih, gi_all, dh, h_all, htag, hdone);
  k_mid<<<256, 512, 0, stream>>>(w_hh, gi_all, b_hh, h_all, htag, hdone, d_hf,
                                 enc, mask, out_w, owb, d_attn, mixb);
  k_att_lin<<<dim3(8, 32), 256, 0, stream>>>(h_all, mixb, lin_w, attb);
  k_out<<<4000, 256, 0, stream>>>(attb, owb, out_b, d_scores);
}